// Round 10
// baseline (532.691 us; speedup 1.0000x reference)
//
#include <hip/hip_runtime.h>

#define NN 50000
#define NE 800000
#define NB ((NN + 255) / 256)   // 196 scan blocks

typedef unsigned int uint32;
typedef unsigned short ushort16;

__device__ __forceinline__ ushort16 f2bf(float f) {
    uint32 u = __float_as_uint(f);
    u += 0x7fff + ((u >> 16) & 1);      // round-to-nearest-even
    return (ushort16)(u >> 16);
}
__device__ __forceinline__ float bf2f(ushort16 h) {
    return __uint_as_float(((uint32)h) << 16);
}

// ---------------------------------------------------------------------------
// k_lin12: a = x@W1 + b1 (fp32 + bf16 copy) ; skip = x@W2 + b2
// ---------------------------------------------------------------------------
__global__ __launch_bounds__(256) void k_lin12(
    const float* __restrict__ x,
    const float* __restrict__ w1, const float* __restrict__ b1,
    const float* __restrict__ w2, const float* __restrict__ b2,
    float* __restrict__ a, ushort16* __restrict__ ab, float* __restrict__ skip)
{
    __shared__ float xs[32][128];
    const int tid = threadIdx.x;
    const int row0 = blockIdx.x * 32;
    for (int i = tid; i < 32 * 128; i += 256) {
        const int gr = row0 + (i >> 7);
        ((float*)xs)[i] = (gr < NN) ? x[gr * 128 + (i & 127)] : 0.f;
    }
    __syncthreads();

    const int col = tid & 63;
    const int g = tid >> 6;
    float acc1[8], acc2[8];
#pragma unroll
    for (int r = 0; r < 8; ++r) { acc1[r] = 0.f; acc2[r] = 0.f; }

#pragma unroll 2
    for (int k0 = 0; k0 < 128; k0 += 4) {
        float wr1[4], wr2[4];
#pragma unroll
        for (int kk = 0; kk < 4; ++kk) {
            wr1[kk] = w1[(k0 + kk) * 64 + col];
            wr2[kk] = w2[(k0 + kk) * 64 + col];
        }
#pragma unroll
        for (int r = 0; r < 8; ++r) {
            const float4 xv = *(const float4*)&xs[g * 8 + r][k0];
            acc1[r] += xv.x * wr1[0] + xv.y * wr1[1] + xv.z * wr1[2] + xv.w * wr1[3];
            acc2[r] += xv.x * wr2[0] + xv.y * wr2[1] + xv.z * wr2[2] + xv.w * wr2[3];
        }
    }

    const float bv1 = b1[col];
    const float bv2 = b2[col];
#pragma unroll
    for (int r = 0; r < 8; ++r) {
        const int gr = row0 + g * 8 + r;
        if (gr < NN) {
            const float v1 = acc1[r] + bv1;
            a[gr * 64 + col]    = v1;
            ab[gr * 64 + col]   = f2bf(v1);
            skip[gr * 64 + col] = acc2[r] + bv2;
        }
    }
}

// ---------------------------------------------------------------------------
// k_t: t[n,h] = a[n,:] @ u[:,h]   ([NN,64]@[64,4]) — one thread per (n,h)
// ---------------------------------------------------------------------------
__global__ __launch_bounds__(256) void k_t(
    const float* __restrict__ a, const float* __restrict__ u,
    float* __restrict__ t)
{
    const int gid = blockIdx.x * 256 + threadIdx.x;
    if (gid >= NN * 4) return;
    const int n = gid >> 2, h = gid & 3;
    const float* ar = a + n * 64;
    float s = 0.f;
#pragma unroll 4
    for (int k = 0; k < 64; ++k) s += ar[k] * u[k * 4 + h];
    t[gid] = s;
}

// ---------------------------------------------------------------------------
// k_lin3: out = h@W + b   ([NN,64]@[64,64])
// ---------------------------------------------------------------------------
__global__ __launch_bounds__(256) void k_lin3(
    const float* __restrict__ h,
    const float* __restrict__ w, const float* __restrict__ b,
    float* __restrict__ out)
{
    __shared__ float hs[32][64];
    const int tid = threadIdx.x;
    const int row0 = blockIdx.x * 32;
    for (int i = tid; i < 32 * 64; i += 256) {
        const int gr = row0 + (i >> 6);
        ((float*)hs)[i] = (gr < NN) ? h[gr * 64 + (i & 63)] : 0.f;
    }
    __syncthreads();

    const int col = tid & 63;
    const int g = tid >> 6;
    float acc[8];
#pragma unroll
    for (int r = 0; r < 8; ++r) acc[r] = 0.f;

#pragma unroll 2
    for (int k0 = 0; k0 < 64; k0 += 4) {
        float wr[4];
#pragma unroll
        for (int kk = 0; kk < 4; ++kk)
            wr[kk] = w[(k0 + kk) * 64 + col];
#pragma unroll
        for (int r = 0; r < 8; ++r) {
            const float4 xv = *(const float4*)&hs[g * 8 + r][k0];
            acc[r] += xv.x * wr[0] + xv.y * wr[1] + xv.z * wr[2] + xv.w * wr[3];
        }
    }

    const float bv = b[col];
#pragma unroll
    for (int r = 0; r < 8; ++r) {
        const int gr = row0 + g * 8 + r;
        if (gr < NN) out[gr * 64 + col] = acc[r] + bv;
    }
}

// ---------------------------------------------------------------------------
// CSR build: histogram -> hierarchical scan -> scatter (src only, 4B)
// ---------------------------------------------------------------------------
__global__ __launch_bounds__(256) void k_hist(const int* __restrict__ ei,
                                              int* __restrict__ deg)
{
    const int i = blockIdx.x * 256 + threadIdx.x;
    if (i < NE) atomicAdd(&deg[ei[NE + i]], 1);
}

__global__ __launch_bounds__(256) void k_blocksum(const int* __restrict__ deg,
                                                  int* __restrict__ bsum)
{
    __shared__ int red[256];
    const int t = threadIdx.x;
    const int i = blockIdx.x * 256 + t;
    red[t] = (i < NN) ? deg[i] : 0;
    __syncthreads();
    for (int off = 128; off > 0; off >>= 1) {
        if (t < off) red[t] += red[t + off];
        __syncthreads();
    }
    if (t == 0) bsum[blockIdx.x] = red[0];
}

__global__ __launch_bounds__(256) void k_scanb(int* __restrict__ bsum)
{
    __shared__ int s[256];
    const int t = threadIdx.x;
    s[t] = (t < NB) ? bsum[t] : 0;
    __syncthreads();
    for (int off = 1; off < 256; off <<= 1) {
        const int v = (t >= off) ? s[t - off] : 0;
        __syncthreads();
        s[t] += v;
        __syncthreads();
    }
    if (t < NB) bsum[t] = (t == 0) ? 0 : s[t - 1];
}

__global__ __launch_bounds__(256) void k_scanfin(const int* __restrict__ deg,
                                                 const int* __restrict__ bsum,
                                                 int* __restrict__ row_ptr,
                                                 int* __restrict__ fill)
{
    __shared__ int s[256];
    const int t = threadIdx.x;
    const int i = blockIdx.x * 256 + t;
    const int v = (i < NN) ? deg[i] : 0;
    s[t] = v;
    __syncthreads();
    for (int off = 1; off < 256; off <<= 1) {
        const int u = (t >= off) ? s[t - off] : 0;
        __syncthreads();
        s[t] += u;
        __syncthreads();
    }
    const int excl = s[t] - v + bsum[blockIdx.x];
    if (i < NN) { row_ptr[i] = excl; fill[i] = excl; }
    if (i == NN - 1) row_ptr[NN] = excl + v;
}

__global__ __launch_bounds__(256) void k_scatter(const int* __restrict__ ei,
                                                 int* __restrict__ fill,
                                                 int* __restrict__ ssrc)
{
    const int i = blockIdx.x * 256 + threadIdx.x;
    if (i >= NE) return;
    const int src = ei[i];
    const int dst = ei[NE + i];
    const int pos = atomicAdd(&fill[dst], 1);
    ssrc[pos] = src;
}

// ---------------------------------------------------------------------------
// k_conv: fused FeaStConv layer. Block = 32 nodes; wave g owns rows
// g*8..g*8+7 and walks their CONTIGUOUS CSR edge range in 64-edge chunks:
//  phase 1 (full 64-lane util): lane i computes edge base+i's softmax q
//    (dst row found against the 8 row boundaries held in registers),
//    writes q float4 + packed {src,dstl} to per-wave LDS buffers.
//  phase 2: serial sweep, register z flushed to zs on (uniform) row change;
//    per edge: 2 uniform ds_reads + 1 bf16 gather + 4 FMA, unrolled 4x.
//  phase B: dense GEMM zs[32,256] @ Wp[256,64] with fused epilogue.
// ---------------------------------------------------------------------------
__global__ __launch_bounds__(256) void k_conv(
    const int* __restrict__ row_ptr, const int* __restrict__ ssrc,
    const float* __restrict__ t, const ushort16* __restrict__ ab,
    const float* __restrict__ c, const float* __restrict__ w,
    const float* __restrict__ bias, const float* __restrict__ skip,
    float* __restrict__ out, ushort16* __restrict__ outb)
{
    __shared__ float zs[32][256];    // 32 KB
    __shared__ float qq[4][64][4];   // 4 KB  per-wave q buffer
    __shared__ uint32 mm[4][64];     // 1 KB  per-wave {src | dstl<<16}

    const int tid = threadIdx.x;
    const int lane = tid & 63;
    const int g = tid >> 6;
    const int row0 = blockIdx.x * 32;
    const int nodeBase = row0 + g * 8;
    const float4 tc = *(const float4*)c;

    // ---- row boundaries rp[0..8] for this wave (clamped) ----
    int rpv = 0;
    if (lane < 9) rpv = row_ptr[min(nodeBase + lane, NN)];
    int rp[9];
#pragma unroll
    for (int i = 0; i < 9; ++i) rp[i] = __shfl(rpv, i, 64);

    // ---- zero this wave's zs rows (covers deg-0 rows) ----
#pragma unroll
    for (int r = 0; r < 8; ++r)
        *(float4*)&zs[g * 8 + r][lane * 4] = make_float4(0.f, 0.f, 0.f, 0.f);

    // ---- phase A: edge-contiguous sweep ----
    float z0 = 0.f, z1 = 0.f, z2 = 0.f, z3 = 0.f;
    int cur = -1;
    const int eBeg = rp[0], eEnd = rp[8];

    for (int base = eBeg; base < eEnd; base += 64) {
        const int m = min(64, eEnd - base);

        // phase 1: lane i -> edge base+i (full lane utilization)
        if (lane < m) {
            const int j = base + lane;
            const int src = ssrc[j];
            int dstl = 0;
#pragma unroll
            for (int r = 1; r < 8; ++r) dstl += (j >= rp[r]) ? 1 : 0;
            const int dg = rp[dstl + 1] - rp[dstl];
            const float invdeg = 1.f / (float)max(dg, 1);
            const float4 ts = ((const float4*)t)[src];
            const float4 td = ((const float4*)t)[nodeBase + dstl];
            const float l0 = ts.x - td.x + tc.x;
            const float l1 = ts.y - td.y + tc.y;
            const float l2 = ts.z - td.z + tc.z;
            const float l3 = ts.w - td.w + tc.w;
            const float mx = fmaxf(fmaxf(l0, l1), fmaxf(l2, l3));
            const float e0 = __expf(l0 - mx);
            const float e1 = __expf(l1 - mx);
            const float e2 = __expf(l2 - mx);
            const float e3 = __expf(l3 - mx);
            const float s = invdeg / (e0 + e1 + e2 + e3);
            *(float4*)&qq[g][lane][0] = make_float4(e0 * s, e1 * s, e2 * s, e3 * s);
            mm[g][lane] = (uint32)src | ((uint32)dstl << 16);
        }
        // same-wave LDS ordering: hardware DS ops are in-order per wave

        // phase 2: serial sweep, 4-edge unroll for gather MLP
        int e = 0;
        for (; e + 3 < m; e += 4) {
#pragma unroll
            for (int k = 0; k < 4; ++k) {
                const uint32 meta = mm[g][e + k];
                const float4 q = *(const float4*)&qq[g][e + k][0];
                const int se = (int)(meta & 0xffffu);
                const int dl = (int)(meta >> 16);
                if (dl != cur) {
                    if (cur >= 0)
                        *(float4*)&zs[g * 8 + cur][lane * 4] =
                            make_float4(z0, z1, z2, z3);
                    cur = dl; z0 = z1 = z2 = z3 = 0.f;
                }
                const float av = bf2f(ab[se * 64 + lane]);
                z0 += q.x * av; z1 += q.y * av; z2 += q.z * av; z3 += q.w * av;
            }
        }
        for (; e < m; ++e) {
            const uint32 meta = mm[g][e];
            const float4 q = *(const float4*)&qq[g][e][0];
            const int se = (int)(meta & 0xffffu);
            const int dl = (int)(meta >> 16);
            if (dl != cur) {
                if (cur >= 0)
                    *(float4*)&zs[g * 8 + cur][lane * 4] =
                        make_float4(z0, z1, z2, z3);
                cur = dl; z0 = z1 = z2 = z3 = 0.f;
            }
            const float av = bf2f(ab[se * 64 + lane]);
            z0 += q.x * av; z1 += q.y * av; z2 += q.z * av; z3 += q.w * av;
        }
    }
    if (cur >= 0)
        *(float4*)&zs[g * 8 + cur][lane * 4] = make_float4(z0, z1, z2, z3);
    __syncthreads();

    // ---- phase B: GEMM zs[32,256] @ Wp[256,64] + epilogue ----
    const int col = lane;
    float acc[8];
#pragma unroll
    for (int r = 0; r < 8; ++r) acc[r] = 0.f;

    for (int k0 = 0; k0 < 256; k0 += 8) {
        float wr[8];
#pragma unroll
        for (int kk = 0; kk < 8; ++kk) {
            const int idx = k0 + kk;     // idx = f*4+h
            wr[kk] = w[(idx >> 2) * 256 + (idx & 3) * 64 + col];
        }
#pragma unroll
        for (int r = 0; r < 8; ++r) {
            const float4 za = *(const float4*)&zs[g * 8 + r][k0];     // broadcast
            const float4 zb = *(const float4*)&zs[g * 8 + r][k0 + 4];
            acc[r] += za.x * wr[0] + za.y * wr[1] + za.z * wr[2] + za.w * wr[3]
                    + zb.x * wr[4] + zb.y * wr[5] + zb.z * wr[6] + zb.w * wr[7];
        }
    }

    const float bv = bias[col];
#pragma unroll
    for (int r = 0; r < 8; ++r) {
        const int gr = row0 + g * 8 + r;
        if (gr < NN) {
            const float v = fmaxf(acc[r] + bv + skip[gr * 64 + col], 0.f);
            out[gr * 64 + col]  = v;
            outb[gr * 64 + col] = f2bf(v);
        }
    }
}

extern "C" void kernel_launch(void* const* d_in, const int* in_sizes, int n_in,
                              void* d_out, int out_size, void* d_ws, size_t ws_size,
                              hipStream_t stream) {
    const float* x       = (const float*)d_in[0];
    const int*   ei      = (const int*)d_in[1];   // [2, NE] int32
    const float* lin1_w  = (const float*)d_in[2];
    const float* lin1_b  = (const float*)d_in[3];
    const float* lin2_w  = (const float*)d_in[4];
    const float* lin2_b  = (const float*)d_in[5];
    const float* lin3_w  = (const float*)d_in[6];
    const float* lin3_b  = (const float*)d_in[7];
    const float* conv1_w = (const float*)d_in[8];
    const float* conv1_u = (const float*)d_in[9];
    const float* conv1_c = (const float*)d_in[10];
    const float* conv1_bias = (const float*)d_in[11];
    const float* conv2_w = (const float*)d_in[12];
    const float* conv2_u = (const float*)d_in[13];
    const float* conv2_c = (const float*)d_in[14];
    const float* conv2_bias = (const float*)d_in[15];
    float* out = (float*)d_out;

    // workspace layout (~44 MB, 16B-aligned sections)
    char* p = (char*)d_ws;
    float* a       = (float*)p;          p += (size_t)NN * 64 * 4;   // fp32 a / h
    float* skip    = (float*)p;          p += (size_t)NN * 64 * 4;
    float* tt      = (float*)p;          p += (size_t)NN * 4 * 4;
    ushort16* ab   = (ushort16*)p;       p += (size_t)NN * 64 * 2;   // bf16 a / h
    ushort16* obsc = (ushort16*)p;       p += (size_t)NN * 64 * 2;   // scratch outb (L2)
    int* ssrc      = (int*)p;            p += (size_t)NE * 4;
    int* deg       = (int*)p;            p += (size_t)NN * 4;
    int* row_ptr   = (int*)p;            p += (size_t)(NN + 1) * 4;
    int* fill      = (int*)p;            p += (size_t)NN * 4;
    int* bsum      = (int*)p;

    // ---- CSR build (edge_index identical for both layers) ----
    hipMemsetAsync(deg, 0, (size_t)NN * sizeof(int), stream);
    k_hist<<<(NE + 255) / 256, 256, 0, stream>>>(ei, deg);
    k_blocksum<<<NB, 256, 0, stream>>>(deg, bsum);
    k_scanb<<<1, 256, 0, stream>>>(bsum);
    k_scanfin<<<NB, 256, 0, stream>>>(deg, bsum, row_ptr, fill);
    k_scatter<<<(NE + 255) / 256, 256, 0, stream>>>(ei, fill, ssrc);

    // ---- layer 1 ----
    k_lin12<<<(NN + 31) / 32, 256, 0, stream>>>(x, lin1_w, lin1_b, lin2_w, lin2_b,
                                                a, ab, skip);
    k_t<<<(NN * 4 + 255) / 256, 256, 0, stream>>>(a, conv1_u, tt);
    k_conv<<<(NN + 31) / 32, 256, 0, stream>>>(row_ptr, ssrc, tt, ab, conv1_c,
                                               conv1_w, conv1_bias, skip, a, obsc);

    // ---- layer 2 ---- (h fp32 in a, bf16 in obsc)
    k_t<<<(NN * 4 + 255) / 256, 256, 0, stream>>>(a, conv2_u, tt);
    k_lin3<<<(NN + 31) / 32, 256, 0, stream>>>(a, lin3_w, lin3_b, skip);
    k_conv<<<(NN + 31) / 32, 256, 0, stream>>>(row_ptr, ssrc, tt, obsc, conv2_c,
                                               conv2_w, conv2_bias, skip, out, ab);
}

// Round 11
// 417.542 us; speedup vs baseline: 1.2758x; 1.2758x over previous
//
#include <hip/hip_runtime.h>

#define NN 50000
#define NE 800000
#define NB ((NN + 255) / 256)   // 196 scan blocks

typedef unsigned int uint32;
typedef unsigned short ushort16;
typedef __attribute__((ext_vector_type(8))) short bf16x8;
typedef __attribute__((ext_vector_type(4))) float f32x4;

__device__ __forceinline__ ushort16 f2bf(float f) {
    uint32 u = __float_as_uint(f);
    u += 0x7fff + ((u >> 16) & 1);      // round-to-nearest-even
    return (ushort16)(u >> 16);
}
__device__ __forceinline__ float bf2f(ushort16 h) {
    return __uint_as_float(((uint32)h) << 16);
}

// ---------------------------------------------------------------------------
// k_lin12: a = x@W1 + b1 (fp32 + bf16 copy) ; skip = x@W2 + b2
// ---------------------------------------------------------------------------
__global__ __launch_bounds__(256) void k_lin12(
    const float* __restrict__ x,
    const float* __restrict__ w1, const float* __restrict__ b1,
    const float* __restrict__ w2, const float* __restrict__ b2,
    float* __restrict__ a, ushort16* __restrict__ ab, float* __restrict__ skip)
{
    __shared__ float xs[32][128];
    const int tid = threadIdx.x;
    const int row0 = blockIdx.x * 32;
    for (int i = tid; i < 32 * 128; i += 256) {
        const int gr = row0 + (i >> 7);
        ((float*)xs)[i] = (gr < NN) ? x[gr * 128 + (i & 127)] : 0.f;
    }
    __syncthreads();

    const int col = tid & 63;
    const int g = tid >> 6;
    float acc1[8], acc2[8];
#pragma unroll
    for (int r = 0; r < 8; ++r) { acc1[r] = 0.f; acc2[r] = 0.f; }

#pragma unroll 2
    for (int k0 = 0; k0 < 128; k0 += 4) {
        float wr1[4], wr2[4];
#pragma unroll
        for (int kk = 0; kk < 4; ++kk) {
            wr1[kk] = w1[(k0 + kk) * 64 + col];
            wr2[kk] = w2[(k0 + kk) * 64 + col];
        }
#pragma unroll
        for (int r = 0; r < 8; ++r) {
            const float4 xv = *(const float4*)&xs[g * 8 + r][k0];
            acc1[r] += xv.x * wr1[0] + xv.y * wr1[1] + xv.z * wr1[2] + xv.w * wr1[3];
            acc2[r] += xv.x * wr2[0] + xv.y * wr2[1] + xv.z * wr2[2] + xv.w * wr2[3];
        }
    }

    const float bv1 = b1[col];
    const float bv2 = b2[col];
#pragma unroll
    for (int r = 0; r < 8; ++r) {
        const int gr = row0 + g * 8 + r;
        if (gr < NN) {
            const float v1 = acc1[r] + bv1;
            a[gr * 64 + col]    = v1;
            ab[gr * 64 + col]   = f2bf(v1);
            skip[gr * 64 + col] = acc2[r] + bv2;
        }
    }
}

// ---------------------------------------------------------------------------
// k_t: t[n,h] = a[n,:] @ u[:,h]   ([NN,64]@[64,4]) — one thread per (n,h)
// ---------------------------------------------------------------------------
__global__ __launch_bounds__(256) void k_t(
    const float* __restrict__ a, const float* __restrict__ u,
    float* __restrict__ t)
{
    const int gid = blockIdx.x * 256 + threadIdx.x;
    if (gid >= NN * 4) return;
    const int n = gid >> 2, h = gid & 3;
    const float* ar = a + n * 64;
    float s = 0.f;
#pragma unroll 4
    for (int k = 0; k < 64; ++k) s += ar[k] * u[k * 4 + h];
    t[gid] = s;
}

// ---------------------------------------------------------------------------
// k_lin3: out = h@W + b   ([NN,64]@[64,64])
// ---------------------------------------------------------------------------
__global__ __launch_bounds__(256) void k_lin3(
    const float* __restrict__ h,
    const float* __restrict__ w, const float* __restrict__ b,
    float* __restrict__ out)
{
    __shared__ float hs[32][64];
    const int tid = threadIdx.x;
    const int row0 = blockIdx.x * 32;
    for (int i = tid; i < 32 * 64; i += 256) {
        const int gr = row0 + (i >> 6);
        ((float*)hs)[i] = (gr < NN) ? h[gr * 64 + (i & 63)] : 0.f;
    }
    __syncthreads();

    const int col = tid & 63;
    const int g = tid >> 6;
    float acc[8];
#pragma unroll
    for (int r = 0; r < 8; ++r) acc[r] = 0.f;

#pragma unroll 2
    for (int k0 = 0; k0 < 64; k0 += 4) {
        float wr[4];
#pragma unroll
        for (int kk = 0; kk < 4; ++kk)
            wr[kk] = w[(k0 + kk) * 64 + col];
#pragma unroll
        for (int r = 0; r < 8; ++r) {
            const float4 xv = *(const float4*)&hs[g * 8 + r][k0];
            acc[r] += xv.x * wr[0] + xv.y * wr[1] + xv.z * wr[2] + xv.w * wr[3];
        }
    }

    const float bv = b[col];
#pragma unroll
    for (int r = 0; r < 8; ++r) {
        const int gr = row0 + g * 8 + r;
        if (gr < NN) out[gr * 64 + col] = acc[r] + bv;
    }
}

// ---------------------------------------------------------------------------
// CSR build: histogram -> hierarchical scan -> scatter (src only, 4B)
// ---------------------------------------------------------------------------
__global__ __launch_bounds__(256) void k_hist(const int* __restrict__ ei,
                                              int* __restrict__ deg)
{
    const int i = blockIdx.x * 256 + threadIdx.x;
    if (i < NE) atomicAdd(&deg[ei[NE + i]], 1);
}

__global__ __launch_bounds__(256) void k_blocksum(const int* __restrict__ deg,
                                                  int* __restrict__ bsum)
{
    __shared__ int red[256];
    const int t = threadIdx.x;
    const int i = blockIdx.x * 256 + t;
    red[t] = (i < NN) ? deg[i] : 0;
    __syncthreads();
    for (int off = 128; off > 0; off >>= 1) {
        if (t < off) red[t] += red[t + off];
        __syncthreads();
    }
    if (t == 0) bsum[blockIdx.x] = red[0];
}

__global__ __launch_bounds__(256) void k_scanb(int* __restrict__ bsum)
{
    __shared__ int s[256];
    const int t = threadIdx.x;
    s[t] = (t < NB) ? bsum[t] : 0;
    __syncthreads();
    for (int off = 1; off < 256; off <<= 1) {
        const int v = (t >= off) ? s[t - off] : 0;
        __syncthreads();
        s[t] += v;
        __syncthreads();
    }
    if (t < NB) bsum[t] = (t == 0) ? 0 : s[t - 1];
}

__global__ __launch_bounds__(256) void k_scanfin(const int* __restrict__ deg,
                                                 const int* __restrict__ bsum,
                                                 int* __restrict__ row_ptr,
                                                 int* __restrict__ fill)
{
    __shared__ int s[256];
    const int t = threadIdx.x;
    const int i = blockIdx.x * 256 + t;
    const int v = (i < NN) ? deg[i] : 0;
    s[t] = v;
    __syncthreads();
    for (int off = 1; off < 256; off <<= 1) {
        const int u = (t >= off) ? s[t - off] : 0;
        __syncthreads();
        s[t] += u;
        __syncthreads();
    }
    const int excl = s[t] - v + bsum[blockIdx.x];
    if (i < NN) { row_ptr[i] = excl; fill[i] = excl; }
    if (i == NN - 1) row_ptr[NN] = excl + v;
}

__global__ __launch_bounds__(256) void k_scatter(const int* __restrict__ ei,
                                                 int* __restrict__ fill,
                                                 int* __restrict__ ssrc)
{
    const int i = blockIdx.x * 256 + threadIdx.x;
    if (i >= NE) return;
    const int src = ei[i];
    const int dst = ei[NE + i];
    const int pos = atomicAdd(&fill[dst], 1);
    ssrc[pos] = src;
}

// ---------------------------------------------------------------------------
// k_agg (R8-proven): one wave per dst node, lane = input-dim f. Aggregates
// z_h[f] = sum_e q_eh * a_bf16[src_e][f]; softmax lane-parallel per 64-edge
// chunk, broadcast via shfl; mean folded into q. Writes zcat[node][f*4+h]
// bf16 as one coalesced uint2/lane.
// ---------------------------------------------------------------------------
__global__ __launch_bounds__(256) void k_agg(
    const int* __restrict__ row_ptr, const int* __restrict__ ssrc,
    const float* __restrict__ t, const ushort16* __restrict__ ab,
    const float* __restrict__ c, uint2* __restrict__ zcat)
{
    const int lane = threadIdx.x & 63;
    const int node = (blockIdx.x * 256 + threadIdx.x) >> 6;
    if (node >= NN) return;

    const int r0 = row_ptr[node];
    const int r1 = row_ptr[node + 1];
    const int deg = r1 - r0;
    const float invdeg = (deg > 0) ? 1.f / (float)deg : 0.f;

    const float4 tc = *(const float4*)c;
    const float4 td = ((const float4*)t)[node];

    float z0 = 0.f, z1 = 0.f, z2 = 0.f, z3 = 0.f;
    for (int base = r0; base < r1; base += 64) {
        const int m = min(64, r1 - base);

        int src = 0;
        float q0 = 0.f, q1 = 0.f, q2 = 0.f, q3 = 0.f;
        if (lane < m) {
            src = ssrc[base + lane];
            const float4 ts = ((const float4*)t)[src];
            const float l0 = ts.x - td.x + tc.x;
            const float l1 = ts.y - td.y + tc.y;
            const float l2 = ts.z - td.z + tc.z;
            const float l3 = ts.w - td.w + tc.w;
            const float mx = fmaxf(fmaxf(l0, l1), fmaxf(l2, l3));
            const float e0 = __expf(l0 - mx);
            const float e1 = __expf(l1 - mx);
            const float e2 = __expf(l2 - mx);
            const float e3 = __expf(l3 - mx);
            const float s = invdeg / (e0 + e1 + e2 + e3);
            q0 = e0 * s; q1 = e1 * s; q2 = e2 * s; q3 = e3 * s;
        }

        int e = 0;
        for (; e + 3 < m; e += 4) {
#pragma unroll
            for (int k = 0; k < 4; ++k) {
                const int se = __shfl(src, e + k, 64);
                const float a0 = __shfl(q0, e + k, 64);
                const float a1 = __shfl(q1, e + k, 64);
                const float a2 = __shfl(q2, e + k, 64);
                const float a3 = __shfl(q3, e + k, 64);
                const float av = bf2f(ab[se * 64 + lane]);
                z0 += a0 * av; z1 += a1 * av; z2 += a2 * av; z3 += a3 * av;
            }
        }
        for (; e < m; ++e) {
            const int se = __shfl(src, e, 64);
            const float a0 = __shfl(q0, e, 64);
            const float a1 = __shfl(q1, e, 64);
            const float a2 = __shfl(q2, e, 64);
            const float a3 = __shfl(q3, e, 64);
            const float av = bf2f(ab[se * 64 + lane]);
            z0 += a0 * av; z1 += a1 * av; z2 += a2 * av; z3 += a3 * av;
        }
    }

    uint2 pk;
    pk.x = (uint32)f2bf(z0) | ((uint32)f2bf(z1) << 16);
    pk.y = (uint32)f2bf(z2) | ((uint32)f2bf(z3) << 16);
    zcat[node * 64 + lane] = pk;   // zcat[node][f*4+h], coalesced 512B/wave
}

// ---------------------------------------------------------------------------
// k_post (MFMA): out = relu(zcat @ Wp + bias + skip) + bf16 copy.
// zcat[n, idx] bf16, idx=f*4+h; Wp[idx][col] = w[(idx>>2)*256+(idx&3)*64+col].
// mfma_f32_16x16x32_bf16; W repacked once/block into LDS in B-frag order
// (B[k=quad*8+j][n=lane&15]); A-frags straight from zcat (16B loads,
// A[m=lane&15][k=quad*8+j]); C/D: col=lane&15, row=quad*4+reg.
// 4 waves x 16 rows = 64 rows/block. Zero unpack ops in the K-loop.
// ---------------------------------------------------------------------------
__global__ __launch_bounds__(256) void k_post(
    const ushort16* __restrict__ zcat, const float* __restrict__ w,
    const float* __restrict__ bias, const float* __restrict__ skip,
    float* __restrict__ out, ushort16* __restrict__ outb)
{
    __shared__ ushort16 wb[16384];   // [c][s][lane][j] B-fragments, 32 KB
    const int tid = threadIdx.x;

    // repack W (fp32, head-interleaved) -> bf16 B-fragment order
    for (int i = tid; i < 16384; i += 256) {
        const int j  = i & 7;
        const int ln = (i >> 3) & 63;
        const int s  = (i >> 9) & 7;
        const int cc = i >> 12;
        const int k  = s * 32 + ((ln >> 4) * 8) + j;   // zcat idx (k-dim)
        const int n  = cc * 16 + (ln & 15);            // output col
        wb[i] = f2bf(w[(k >> 2) * 256 + (k & 3) * 64 + n]);
    }
    __syncthreads();

    const int lane = tid & 63;
    const int g = tid >> 6;
    const int m = lane & 15;
    const int quad = lane >> 4;
    const int rowBase = blockIdx.x * 64 + g * 16;

    const int arow = min(rowBase + m, NN - 1);
    const ushort16* zrow = zcat + (size_t)arow * 256 + quad * 8;

    f32x4 acc[4];
#pragma unroll
    for (int c = 0; c < 4; ++c)
#pragma unroll
        for (int r = 0; r < 4; ++r) acc[c][r] = 0.f;

#pragma unroll
    for (int s = 0; s < 8; ++s) {
        const bf16x8 af = *(const bf16x8*)(zrow + s * 32);
#pragma unroll
        for (int c = 0; c < 4; ++c) {
            const bf16x8 bf = *(const bf16x8*)&wb[((c * 8 + s) * 64 + lane) * 8];
            acc[c] = __builtin_amdgcn_mfma_f32_16x16x32_bf16(af, bf, acc[c], 0, 0, 0);
        }
    }

    // epilogue: row = quad*4+reg, col = c*16+m
#pragma unroll
    for (int c = 0; c < 4; ++c) {
        const int colg = c * 16 + m;
        const float bv = bias[colg];
#pragma unroll
        for (int reg = 0; reg < 4; ++reg) {
            const int gr = rowBase + quad * 4 + reg;
            if (gr < NN) {
                const float v = fmaxf(acc[c][reg] + bv + skip[gr * 64 + colg], 0.f);
                out[gr * 64 + colg]  = v;
                outb[gr * 64 + colg] = f2bf(v);
            }
        }
    }
}

extern "C" void kernel_launch(void* const* d_in, const int* in_sizes, int n_in,
                              void* d_out, int out_size, void* d_ws, size_t ws_size,
                              hipStream_t stream) {
    const float* x       = (const float*)d_in[0];
    const int*   ei      = (const int*)d_in[1];   // [2, NE] int32
    const float* lin1_w  = (const float*)d_in[2];
    const float* lin1_b  = (const float*)d_in[3];
    const float* lin2_w  = (const float*)d_in[4];
    const float* lin2_b  = (const float*)d_in[5];
    const float* lin3_w  = (const float*)d_in[6];
    const float* lin3_b  = (const float*)d_in[7];
    const float* conv1_w = (const float*)d_in[8];
    const float* conv1_u = (const float*)d_in[9];
    const float* conv1_c = (const float*)d_in[10];
    const float* conv1_bias = (const float*)d_in[11];
    const float* conv2_w = (const float*)d_in[12];
    const float* conv2_u = (const float*)d_in[13];
    const float* conv2_c = (const float*)d_in[14];
    const float* conv2_bias = (const float*)d_in[15];
    float* out = (float*)d_out;

    // workspace layout (~62 MB, 16B-aligned sections)
    char* p = (char*)d_ws;
    float* a      = (float*)p;           p += (size_t)NN * 64 * 4;   // fp32 a / h
    float* skip   = (float*)p;           p += (size_t)NN * 64 * 4;
    float* tt     = (float*)p;           p += (size_t)NN * 4 * 4;
    ushort16* ab  = (ushort16*)p;        p += (size_t)NN * 64 * 2;   // bf16 a / h
    ushort16* zc  = (ushort16*)p;        p += (size_t)NN * 256 * 2;  // bf16 z
    int* ssrc     = (int*)p;             p += (size_t)NE * 4;
    int* deg      = (int*)p;             p += (size_t)NN * 4;
    int* row_ptr  = (int*)p;             p += (size_t)(NN + 1) * 4;
    int* fill     = (int*)p;             p += (size_t)NN * 4;
    int* bsum     = (int*)p;

    // ---- CSR build (edge_index identical for both layers) ----
    hipMemsetAsync(deg, 0, (size_t)NN * sizeof(int), stream);
    k_hist<<<(NE + 255) / 256, 256, 0, stream>>>(ei, deg);
    k_blocksum<<<NB, 256, 0, stream>>>(deg, bsum);
    k_scanb<<<1, 256, 0, stream>>>(bsum);
    k_scanfin<<<NB, 256, 0, stream>>>(deg, bsum, row_ptr, fill);
    k_scatter<<<(NE + 255) / 256, 256, 0, stream>>>(ei, fill, ssrc);

    // ---- layer 1 ----
    k_lin12<<<(NN + 31) / 32, 256, 0, stream>>>(x, lin1_w, lin1_b, lin2_w, lin2_b,
                                                a, ab, skip);
    k_t<<<(NN * 4 + 255) / 256, 256, 0, stream>>>(a, conv1_u, tt);
    k_agg<<<(NN + 3) / 4, 256, 0, stream>>>(row_ptr, ssrc, tt, ab, conv1_c, (uint2*)zc);
    k_post<<<(NN + 63) / 64, 256, 0, stream>>>(zc, conv1_w, conv1_bias, skip, a, ab);

    // ---- layer 2 ---- (h fp32 in a, bf16 in ab)
    k_t<<<(NN * 4 + 255) / 256, 256, 0, stream>>>(a, conv2_u, tt);
    k_lin3<<<(NN + 31) / 32, 256, 0, stream>>>(a, lin3_w, lin3_b, skip);
    k_agg<<<(NN + 3) / 4, 256, 0, stream>>>(row_ptr, ssrc, tt, ab, conv2_c, (uint2*)zc);
    k_post<<<(NN + 63) / 64, 256, 0, stream>>>(zc, conv2_w, conv2_bias, skip, out, ab);
}

// Round 12
// 390.169 us; speedup vs baseline: 1.3653x; 1.0702x over previous
//
#include <hip/hip_runtime.h>

#define NN 50000
#define NE 800000
#define NB ((NN + 255) / 256)   // 196 scan blocks

typedef unsigned int uint32;
typedef unsigned short ushort16;
typedef __attribute__((ext_vector_type(8))) short bf16x8;
typedef __attribute__((ext_vector_type(4))) float f32x4;

__device__ __forceinline__ ushort16 f2bf(float f) {
    uint32 u = __float_as_uint(f);
    u += 0x7fff + ((u >> 16) & 1);      // round-to-nearest-even
    return (ushort16)(u >> 16);
}
__device__ __forceinline__ float bf2f(ushort16 h) {
    return __uint_as_float(((uint32)h) << 16);
}
__device__ __forceinline__ bf16x8 pack8(const float4 a, const float4 b) {
    union { bf16x8 v; ushort16 u[8]; } r;
    r.u[0] = f2bf(a.x); r.u[1] = f2bf(a.y); r.u[2] = f2bf(a.z); r.u[3] = f2bf(a.w);
    r.u[4] = f2bf(b.x); r.u[5] = f2bf(b.y); r.u[6] = f2bf(b.z); r.u[7] = f2bf(b.w);
    return r.v;
}

// ---------------------------------------------------------------------------
// k_lin12 (MFMA): [a | skip] = x @ [W1 | W2] + [b1 | b2]; a also emitted bf16.
// mfma_f32_16x16x32_bf16. [W1|W2] repacked once/block into LDS B-frag order
// (K=128, N=128, 32 KB bf16). A-frags: x fp32 loaded as 2 float4, packed to
// bf16x8 in registers. 4 waves x 16 rows = 64 rows/block; 32 MFMA/wave.
// C/D: col=lane&15 (+16*c), row=quad*4+reg (verified mapping).
// ---------------------------------------------------------------------------
__global__ __launch_bounds__(256) void k_lin12(
    const float* __restrict__ x,
    const float* __restrict__ w1, const float* __restrict__ b1,
    const float* __restrict__ w2, const float* __restrict__ b2,
    float* __restrict__ a, ushort16* __restrict__ ab, float* __restrict__ skip)
{
    __shared__ ushort16 wb[16384];   // B-frags: ((cc*4+s)*64+ln)*8+j, 32 KB
    const int tid = threadIdx.x;

    for (int i = tid; i < 16384; i += 256) {
        const int j  = i & 7;
        const int ln = (i >> 3) & 63;
        const int s  = (i >> 9) & 3;
        const int cc = i >> 11;
        const int k  = s * 32 + ((ln >> 4) * 8) + j;   // 0..127
        const int n  = cc * 16 + (ln & 15);            // 0..127
        wb[i] = f2bf((n < 64) ? w1[k * 64 + n] : w2[k * 64 + (n - 64)]);
    }
    __syncthreads();

    const int lane = tid & 63;
    const int g = tid >> 6;
    const int m = lane & 15;
    const int quad = lane >> 4;
    const int rowBase = blockIdx.x * 64 + g * 16;

    const int arow = min(rowBase + m, NN - 1);
    const float* xr = x + (size_t)arow * 128 + quad * 8;

    f32x4 acc[8];
#pragma unroll
    for (int c = 0; c < 8; ++c)
#pragma unroll
        for (int r = 0; r < 4; ++r) acc[c][r] = 0.f;

#pragma unroll
    for (int s = 0; s < 4; ++s) {
        const float4 xa = *(const float4*)(xr + s * 32);
        const float4 xb = *(const float4*)(xr + s * 32 + 4);
        const bf16x8 af = pack8(xa, xb);
#pragma unroll
        for (int c = 0; c < 8; ++c) {
            const bf16x8 bf = *(const bf16x8*)&wb[((c * 4 + s) * 64 + lane) * 8];
            acc[c] = __builtin_amdgcn_mfma_f32_16x16x32_bf16(af, bf, acc[c], 0, 0, 0);
        }
    }

#pragma unroll
    for (int c = 0; c < 8; ++c) {
        const int colg = c * 16 + m;
        const float bv = (colg < 64) ? b1[colg] : b2[colg - 64];
#pragma unroll
        for (int reg = 0; reg < 4; ++reg) {
            const int gr = rowBase + quad * 4 + reg;
            if (gr < NN) {
                const float v = acc[c][reg] + bv;
                if (colg < 64) {
                    a[gr * 64 + colg]  = v;
                    ab[gr * 64 + colg] = f2bf(v);
                } else {
                    skip[gr * 64 + (colg - 64)] = v;
                }
            }
        }
    }
}

// ---------------------------------------------------------------------------
// k_t: t[n,h] = a[n,:] @ u[:,h]   ([NN,64]@[64,4]) — one thread per (n,h)
// ---------------------------------------------------------------------------
__global__ __launch_bounds__(256) void k_t(
    const float* __restrict__ a, const float* __restrict__ u,
    float* __restrict__ t)
{
    const int gid = blockIdx.x * 256 + threadIdx.x;
    if (gid >= NN * 4) return;
    const int n = gid >> 2, h = gid & 3;
    const float* ar = a + n * 64;
    float s = 0.f;
#pragma unroll 4
    for (int k = 0; k < 64; ++k) s += ar[k] * u[k * 4 + h];
    t[gid] = s;
}

// ---------------------------------------------------------------------------
// k_lin3: out = h@W + b   ([NN,64]@[64,64])
// ---------------------------------------------------------------------------
__global__ __launch_bounds__(256) void k_lin3(
    const float* __restrict__ h,
    const float* __restrict__ w, const float* __restrict__ b,
    float* __restrict__ out)
{
    __shared__ float hs[32][64];
    const int tid = threadIdx.x;
    const int row0 = blockIdx.x * 32;
    for (int i = tid; i < 32 * 64; i += 256) {
        const int gr = row0 + (i >> 6);
        ((float*)hs)[i] = (gr < NN) ? h[gr * 64 + (i & 63)] : 0.f;
    }
    __syncthreads();

    const int col = tid & 63;
    const int g = tid >> 6;
    float acc[8];
#pragma unroll
    for (int r = 0; r < 8; ++r) acc[r] = 0.f;

#pragma unroll 2
    for (int k0 = 0; k0 < 64; k0 += 4) {
        float wr[4];
#pragma unroll
        for (int kk = 0; kk < 4; ++kk)
            wr[kk] = w[(k0 + kk) * 64 + col];
#pragma unroll
        for (int r = 0; r < 8; ++r) {
            const float4 xv = *(const float4*)&hs[g * 8 + r][k0];
            acc[r] += xv.x * wr[0] + xv.y * wr[1] + xv.z * wr[2] + xv.w * wr[3];
        }
    }

    const float bv = b[col];
#pragma unroll
    for (int r = 0; r < 8; ++r) {
        const int gr = row0 + g * 8 + r;
        if (gr < NN) out[gr * 64 + col] = acc[r] + bv;
    }
}

// ---------------------------------------------------------------------------
// CSR build: histogram -> hierarchical scan -> scatter (src only, 4B)
// ---------------------------------------------------------------------------
__global__ __launch_bounds__(256) void k_hist(const int* __restrict__ ei,
                                              int* __restrict__ deg)
{
    const int i = blockIdx.x * 256 + threadIdx.x;
    if (i < NE) atomicAdd(&deg[ei[NE + i]], 1);
}

__global__ __launch_bounds__(256) void k_blocksum(const int* __restrict__ deg,
                                                  int* __restrict__ bsum)
{
    __shared__ int red[256];
    const int t = threadIdx.x;
    const int i = blockIdx.x * 256 + t;
    red[t] = (i < NN) ? deg[i] : 0;
    __syncthreads();
    for (int off = 128; off > 0; off >>= 1) {
        if (t < off) red[t] += red[t + off];
        __syncthreads();
    }
    if (t == 0) bsum[blockIdx.x] = red[0];
}

__global__ __launch_bounds__(256) void k_scanb(int* __restrict__ bsum)
{
    __shared__ int s[256];
    const int t = threadIdx.x;
    s[t] = (t < NB) ? bsum[t] : 0;
    __syncthreads();
    for (int off = 1; off < 256; off <<= 1) {
        const int v = (t >= off) ? s[t - off] : 0;
        __syncthreads();
        s[t] += v;
        __syncthreads();
    }
    if (t < NB) bsum[t] = (t == 0) ? 0 : s[t - 1];
}

__global__ __launch_bounds__(256) void k_scanfin(const int* __restrict__ deg,
                                                 const int* __restrict__ bsum,
                                                 int* __restrict__ row_ptr,
                                                 int* __restrict__ fill)
{
    __shared__ int s[256];
    const int t = threadIdx.x;
    const int i = blockIdx.x * 256 + t;
    const int v = (i < NN) ? deg[i] : 0;
    s[t] = v;
    __syncthreads();
    for (int off = 1; off < 256; off <<= 1) {
        const int u = (t >= off) ? s[t - off] : 0;
        __syncthreads();
        s[t] += u;
        __syncthreads();
    }
    const int excl = s[t] - v + bsum[blockIdx.x];
    if (i < NN) { row_ptr[i] = excl; fill[i] = excl; }
    if (i == NN - 1) row_ptr[NN] = excl + v;
}

__global__ __launch_bounds__(256) void k_scatter(const int* __restrict__ ei,
                                                 int* __restrict__ fill,
                                                 int* __restrict__ ssrc)
{
    const int i = blockIdx.x * 256 + threadIdx.x;
    if (i >= NE) return;
    const int src = ei[i];
    const int dst = ei[NE + i];
    const int pos = atomicAdd(&fill[dst], 1);
    ssrc[pos] = src;
}

// ---------------------------------------------------------------------------
// k_agg: one wave per dst node, lane = input-dim f. Aggregates
// z_h[f] = sum_e q_eh * a_bf16[src_e][f]; softmax lane-parallel per 64-edge
// chunk, broadcast via shfl; mean folded into q. Writes zcat[node][f*4+h]
// bf16 as one coalesced uint2/lane.
// ---------------------------------------------------------------------------
__global__ __launch_bounds__(256) void k_agg(
    const int* __restrict__ row_ptr, const int* __restrict__ ssrc,
    const float* __restrict__ t, const ushort16* __restrict__ ab,
    const float* __restrict__ c, uint2* __restrict__ zcat)
{
    const int lane = threadIdx.x & 63;
    const int node = (blockIdx.x * 256 + threadIdx.x) >> 6;
    if (node >= NN) return;

    const int r0 = row_ptr[node];
    const int r1 = row_ptr[node + 1];
    const int deg = r1 - r0;
    const float invdeg = (deg > 0) ? 1.f / (float)deg : 0.f;

    const float4 tc = *(const float4*)c;
    const float4 td = ((const float4*)t)[node];

    float z0 = 0.f, z1 = 0.f, z2 = 0.f, z3 = 0.f;
    for (int base = r0; base < r1; base += 64) {
        const int m = min(64, r1 - base);

        int src = 0;
        float q0 = 0.f, q1 = 0.f, q2 = 0.f, q3 = 0.f;
        if (lane < m) {
            src = ssrc[base + lane];
            const float4 ts = ((const float4*)t)[src];
            const float l0 = ts.x - td.x + tc.x;
            const float l1 = ts.y - td.y + tc.y;
            const float l2 = ts.z - td.z + tc.z;
            const float l3 = ts.w - td.w + tc.w;
            const float mx = fmaxf(fmaxf(l0, l1), fmaxf(l2, l3));
            const float e0 = __expf(l0 - mx);
            const float e1 = __expf(l1 - mx);
            const float e2 = __expf(l2 - mx);
            const float e3 = __expf(l3 - mx);
            const float s = invdeg / (e0 + e1 + e2 + e3);
            q0 = e0 * s; q1 = e1 * s; q2 = e2 * s; q3 = e3 * s;
        }

        int e = 0;
        for (; e + 3 < m; e += 4) {
#pragma unroll
            for (int k = 0; k < 4; ++k) {
                const int se = __shfl(src, e + k, 64);
                const float a0 = __shfl(q0, e + k, 64);
                const float a1 = __shfl(q1, e + k, 64);
                const float a2 = __shfl(q2, e + k, 64);
                const float a3 = __shfl(q3, e + k, 64);
                const float av = bf2f(ab[se * 64 + lane]);
                z0 += a0 * av; z1 += a1 * av; z2 += a2 * av; z3 += a3 * av;
            }
        }
        for (; e < m; ++e) {
            const int se = __shfl(src, e, 64);
            const float a0 = __shfl(q0, e, 64);
            const float a1 = __shfl(q1, e, 64);
            const float a2 = __shfl(q2, e, 64);
            const float a3 = __shfl(q3, e, 64);
            const float av = bf2f(ab[se * 64 + lane]);
            z0 += a0 * av; z1 += a1 * av; z2 += a2 * av; z3 += a3 * av;
        }
    }

    uint2 pk;
    pk.x = (uint32)f2bf(z0) | ((uint32)f2bf(z1) << 16);
    pk.y = (uint32)f2bf(z2) | ((uint32)f2bf(z3) << 16);
    zcat[node * 64 + lane] = pk;   // zcat[node][f*4+h], coalesced 512B/wave
}

// ---------------------------------------------------------------------------
// k_post (MFMA): out = relu(zcat @ Wp + bias + skip) + bf16 copy.
// ---------------------------------------------------------------------------
__global__ __launch_bounds__(256) void k_post(
    const ushort16* __restrict__ zcat, const float* __restrict__ w,
    const float* __restrict__ bias, const float* __restrict__ skip,
    float* __restrict__ out, ushort16* __restrict__ outb)
{
    __shared__ ushort16 wb[16384];   // [c][s][lane][j] B-fragments, 32 KB
    const int tid = threadIdx.x;

    // repack W (fp32, head-interleaved) -> bf16 B-fragment order
    for (int i = tid; i < 16384; i += 256) {
        const int j  = i & 7;
        const int ln = (i >> 3) & 63;
        const int s  = (i >> 9) & 7;
        const int cc = i >> 12;
        const int k  = s * 32 + ((ln >> 4) * 8) + j;   // zcat idx (k-dim)
        const int n  = cc * 16 + (ln & 15);            // output col
        wb[i] = f2bf(w[(k >> 2) * 256 + (k & 3) * 64 + n]);
    }
    __syncthreads();

    const int lane = tid & 63;
    const int g = tid >> 6;
    const int m = lane & 15;
    const int quad = lane >> 4;
    const int rowBase = blockIdx.x * 64 + g * 16;

    const int arow = min(rowBase + m, NN - 1);
    const ushort16* zrow = zcat + (size_t)arow * 256 + quad * 8;

    f32x4 acc[4];
#pragma unroll
    for (int c = 0; c < 4; ++c)
#pragma unroll
        for (int r = 0; r < 4; ++r) acc[c][r] = 0.f;

#pragma unroll
    for (int s = 0; s < 8; ++s) {
        const bf16x8 af = *(const bf16x8*)(zrow + s * 32);
#pragma unroll
        for (int c = 0; c < 4; ++c) {
            const bf16x8 bf = *(const bf16x8*)&wb[((c * 8 + s) * 64 + lane) * 8];
            acc[c] = __builtin_amdgcn_mfma_f32_16x16x32_bf16(af, bf, acc[c], 0, 0, 0);
        }
    }

    // epilogue: row = quad*4+reg, col = c*16+m
#pragma unroll
    for (int c = 0; c < 4; ++c) {
        const int colg = c * 16 + m;
        const float bv = bias[colg];
#pragma unroll
        for (int reg = 0; reg < 4; ++reg) {
            const int gr = rowBase + quad * 4 + reg;
            if (gr < NN) {
                const float v = fmaxf(acc[c][reg] + bv + skip[gr * 64 + colg], 0.f);
                out[gr * 64 + colg]  = v;
                outb[gr * 64 + colg] = f2bf(v);
            }
        }
    }
}

extern "C" void kernel_launch(void* const* d_in, const int* in_sizes, int n_in,
                              void* d_out, int out_size, void* d_ws, size_t ws_size,
                              hipStream_t stream) {
    const float* x       = (const float*)d_in[0];
    const int*   ei      = (const int*)d_in[1];   // [2, NE] int32
    const float* lin1_w  = (const float*)d_in[2];
    const float* lin1_b  = (const float*)d_in[3];
    const float* lin2_w  = (const float*)d_in[4];
    const float* lin2_b  = (const float*)d_in[5];
    const float* lin3_w  = (const float*)d_in[6];
    const float* lin3_b  = (const float*)d_in[7];
    const float* conv1_w = (const float*)d_in[8];
    const float* conv1_u = (const float*)d_in[9];
    const float* conv1_c = (const float*)d_in[10];
    const float* conv1_bias = (const float*)d_in[11];
    const float* conv2_w = (const float*)d_in[12];
    const float* conv2_u = (const float*)d_in[13];
    const float* conv2_c = (const float*)d_in[14];
    const float* conv2_bias = (const float*)d_in[15];
    float* out = (float*)d_out;

    // workspace layout (~62 MB, 16B-aligned sections)
    char* p = (char*)d_ws;
    float* a      = (float*)p;           p += (size_t)NN * 64 * 4;   // fp32 a / h
    float* skip   = (float*)p;           p += (size_t)NN * 64 * 4;
    float* tt     = (float*)p;           p += (size_t)NN * 4 * 4;
    ushort16* ab  = (ushort16*)p;        p += (size_t)NN * 64 * 2;   // bf16 a / h
    ushort16* zc  = (ushort16*)p;        p += (size_t)NN * 256 * 2;  // bf16 z
    int* ssrc     = (int*)p;             p += (size_t)NE * 4;
    int* deg      = (int*)p;             p += (size_t)NN * 4;
    int* row_ptr  = (int*)p;             p += (size_t)(NN + 1) * 4;
    int* fill     = (int*)p;             p += (size_t)NN * 4;
    int* bsum     = (int*)p;

    // ---- CSR build (edge_index identical for both layers) ----
    hipMemsetAsync(deg, 0, (size_t)NN * sizeof(int), stream);
    k_hist<<<(NE + 255) / 256, 256, 0, stream>>>(ei, deg);
    k_blocksum<<<NB, 256, 0, stream>>>(deg, bsum);
    k_scanb<<<1, 256, 0, stream>>>(bsum);
    k_scanfin<<<NB, 256, 0, stream>>>(deg, bsum, row_ptr, fill);
    k_scatter<<<(NE + 255) / 256, 256, 0, stream>>>(ei, fill, ssrc);

    // ---- layer 1 ----
    k_lin12<<<(NN + 63) / 64, 256, 0, stream>>>(x, lin1_w, lin1_b, lin2_w, lin2_b,
                                                a, ab, skip);
    k_t<<<(NN * 4 + 255) / 256, 256, 0, stream>>>(a, conv1_u, tt);
    k_agg<<<(NN + 3) / 4, 256, 0, stream>>>(row_ptr, ssrc, tt, ab, conv1_c, (uint2*)zc);
    k_post<<<(NN + 63) / 64, 256, 0, stream>>>(zc, conv1_w, conv1_bias, skip, a, ab);

    // ---- layer 2 ---- (h fp32 in a, bf16 in ab)
    k_t<<<(NN * 4 + 255) / 256, 256, 0, stream>>>(a, conv2_u, tt);
    k_lin3<<<(NN + 31) / 32, 256, 0, stream>>>(a, lin3_w, lin3_b, skip);
    k_agg<<<(NN + 3) / 4, 256, 0, stream>>>(row_ptr, ssrc, tt, ab, conv2_c, (uint2*)zc);
    k_post<<<(NN + 63) / 64, 256, 0, stream>>>(zc, conv2_w, conv2_bias, skip, out, ab);
}

// Round 13
// 354.404 us; speedup vs baseline: 1.5031x; 1.1009x over previous
//
#include <hip/hip_runtime.h>

#define NN 50000
#define NE 800000
#define NB ((NN + 255) / 256)   // 196 scan blocks

typedef unsigned int uint32;
typedef unsigned short ushort16;
typedef __attribute__((ext_vector_type(8))) short bf16x8;
typedef __attribute__((ext_vector_type(4))) float f32x4;

__device__ __forceinline__ ushort16 f2bf(float f) {
    uint32 u = __float_as_uint(f);
    u += 0x7fff + ((u >> 16) & 1);      // round-to-nearest-even
    return (ushort16)(u >> 16);
}
__device__ __forceinline__ float bf2f(ushort16 h) {
    return __uint_as_float(((uint32)h) << 16);
}
__device__ __forceinline__ float bf_lo(uint32 u) {
    return __uint_as_float(u << 16);
}
__device__ __forceinline__ float bf_hi(uint32 u) {
    return __uint_as_float(u & 0xffff0000u);
}
__device__ __forceinline__ bf16x8 pack8(const float4 a, const float4 b) {
    union { bf16x8 v; ushort16 u[8]; } r;
    r.u[0] = f2bf(a.x); r.u[1] = f2bf(a.y); r.u[2] = f2bf(a.z); r.u[3] = f2bf(a.w);
    r.u[4] = f2bf(b.x); r.u[5] = f2bf(b.y); r.u[6] = f2bf(b.z); r.u[7] = f2bf(b.w);
    return r.v;
}

// ---------------------------------------------------------------------------
// Weight pre-pack (once per launch): fp32 -> bf16 B-fragment order tables.
// k_pack12: [W1|W2] K=128,N=128 -> 16384 ushort. idx=((cc*4+s)*64+ln)*8+j.
// k_packp:  head-interleaved conv W K=256,N=64 -> 16384. idx=((c*8+s)*64+ln)*8+j.
// ---------------------------------------------------------------------------
__global__ __launch_bounds__(256) void k_pack12(
    const float* __restrict__ w1, const float* __restrict__ w2,
    ushort16* __restrict__ pw)
{
    const int i = blockIdx.x * 256 + threadIdx.x;   // 0..16383
    const int j  = i & 7;
    const int ln = (i >> 3) & 63;
    const int s  = (i >> 9) & 3;
    const int cc = i >> 11;
    const int k  = s * 32 + ((ln >> 4) * 8) + j;    // 0..127
    const int n  = cc * 16 + (ln & 15);             // 0..127
    pw[i] = f2bf((n < 64) ? w1[k * 64 + n] : w2[k * 64 + (n - 64)]);
}

__global__ __launch_bounds__(256) void k_packp(
    const float* __restrict__ w, ushort16* __restrict__ pw)
{
    const int i = blockIdx.x * 256 + threadIdx.x;   // 0..16383
    const int j  = i & 7;
    const int ln = (i >> 3) & 63;
    const int s  = (i >> 9) & 7;
    const int cc = i >> 12;
    const int k  = s * 32 + ((ln >> 4) * 8) + j;    // zcat idx (k-dim)
    const int n  = cc * 16 + (ln & 15);             // output col
    pw[i] = f2bf(w[(k >> 2) * 256 + (k & 3) * 64 + n]);
}

// ---------------------------------------------------------------------------
// k_lin12 (MFMA): [a | skip] = x @ [W1 | W2] + [b1 | b2]; a also emitted bf16.
// B-frags loaded straight from the pre-packed global table (L2-hot) — no LDS.
// 4 waves x 16 rows = 64 rows/block; 32 MFMA/wave.
// C/D: col=lane&15 (+16*c), row=quad*4+reg (verified mapping).
// ---------------------------------------------------------------------------
__global__ __launch_bounds__(256) void k_lin12(
    const float* __restrict__ x, const ushort16* __restrict__ pw,
    const float* __restrict__ b1, const float* __restrict__ b2,
    float* __restrict__ a, ushort16* __restrict__ ab, float* __restrict__ skip)
{
    const int tid = threadIdx.x;
    const int lane = tid & 63;
    const int g = tid >> 6;
    const int m = lane & 15;
    const int quad = lane >> 4;
    const int rowBase = blockIdx.x * 64 + g * 16;

    const int arow = min(rowBase + m, NN - 1);
    const float* xr = x + (size_t)arow * 128 + quad * 8;

    f32x4 acc[8];
#pragma unroll
    for (int c = 0; c < 8; ++c)
#pragma unroll
        for (int r = 0; r < 4; ++r) acc[c][r] = 0.f;

#pragma unroll
    for (int s = 0; s < 4; ++s) {
        const float4 xa = *(const float4*)(xr + s * 32);
        const float4 xb = *(const float4*)(xr + s * 32 + 4);
        const bf16x8 af = pack8(xa, xb);
#pragma unroll
        for (int c = 0; c < 8; ++c) {
            const bf16x8 bf = *(const bf16x8*)&pw[((c * 4 + s) * 64 + lane) * 8];
            acc[c] = __builtin_amdgcn_mfma_f32_16x16x32_bf16(af, bf, acc[c], 0, 0, 0);
        }
    }

#pragma unroll
    for (int c = 0; c < 8; ++c) {
        const int colg = c * 16 + m;
        const float bv = (colg < 64) ? b1[colg] : b2[colg - 64];
#pragma unroll
        for (int reg = 0; reg < 4; ++reg) {
            const int gr = rowBase + quad * 4 + reg;
            if (gr < NN) {
                const float v = acc[c][reg] + bv;
                if (colg < 64) {
                    a[gr * 64 + colg]  = v;
                    ab[gr * 64 + colg] = f2bf(v);
                } else {
                    skip[gr * 64 + (colg - 64)] = v;
                }
            }
        }
    }
}

// ---------------------------------------------------------------------------
// k_t: t[n,h] = a[n,:] @ u[:,h]   ([NN,64]@[64,4]) — one thread per (n,h)
// ---------------------------------------------------------------------------
__global__ __launch_bounds__(256) void k_t(
    const float* __restrict__ a, const float* __restrict__ u,
    float* __restrict__ t)
{
    const int gid = blockIdx.x * 256 + threadIdx.x;
    if (gid >= NN * 4) return;
    const int n = gid >> 2, h = gid & 3;
    const float* ar = a + n * 64;
    float s = 0.f;
#pragma unroll 4
    for (int k = 0; k < 64; ++k) s += ar[k] * u[k * 4 + h];
    t[gid] = s;
}

// ---------------------------------------------------------------------------
// k_lin3: out = h@W + b   ([NN,64]@[64,64])
// ---------------------------------------------------------------------------
__global__ __launch_bounds__(256) void k_lin3(
    const float* __restrict__ h,
    const float* __restrict__ w, const float* __restrict__ b,
    float* __restrict__ out)
{
    __shared__ float hs[32][64];
    const int tid = threadIdx.x;
    const int row0 = blockIdx.x * 32;
    for (int i = tid; i < 32 * 64; i += 256) {
        const int gr = row0 + (i >> 6);
        ((float*)hs)[i] = (gr < NN) ? h[gr * 64 + (i & 63)] : 0.f;
    }
    __syncthreads();

    const int col = tid & 63;
    const int g = tid >> 6;
    float acc[8];
#pragma unroll
    for (int r = 0; r < 8; ++r) acc[r] = 0.f;

#pragma unroll 2
    for (int k0 = 0; k0 < 64; k0 += 4) {
        float wr[4];
#pragma unroll
        for (int kk = 0; kk < 4; ++kk)
            wr[kk] = w[(k0 + kk) * 64 + col];
#pragma unroll
        for (int r = 0; r < 8; ++r) {
            const float4 xv = *(const float4*)&hs[g * 8 + r][k0];
            acc[r] += xv.x * wr[0] + xv.y * wr[1] + xv.z * wr[2] + xv.w * wr[3];
        }
    }

    const float bv = b[col];
#pragma unroll
    for (int r = 0; r < 8; ++r) {
        const int gr = row0 + g * 8 + r;
        if (gr < NN) out[gr * 64 + col] = acc[r] + bv;
    }
}

// ---------------------------------------------------------------------------
// CSR build: histogram -> hierarchical scan -> scatter (src only, 4B)
// ---------------------------------------------------------------------------
__global__ __launch_bounds__(256) void k_hist(const int* __restrict__ ei,
                                              int* __restrict__ deg)
{
    const int i = blockIdx.x * 256 + threadIdx.x;
    if (i < NE) atomicAdd(&deg[ei[NE + i]], 1);
}

__global__ __launch_bounds__(256) void k_blocksum(const int* __restrict__ deg,
                                                  int* __restrict__ bsum)
{
    __shared__ int red[256];
    const int t = threadIdx.x;
    const int i = blockIdx.x * 256 + t;
    red[t] = (i < NN) ? deg[i] : 0;
    __syncthreads();
    for (int off = 128; off > 0; off >>= 1) {
        if (t < off) red[t] += red[t + off];
        __syncthreads();
    }
    if (t == 0) bsum[blockIdx.x] = red[0];
}

__global__ __launch_bounds__(256) void k_scanb(int* __restrict__ bsum)
{
    __shared__ int s[256];
    const int t = threadIdx.x;
    s[t] = (t < NB) ? bsum[t] : 0;
    __syncthreads();
    for (int off = 1; off < 256; off <<= 1) {
        const int v = (t >= off) ? s[t - off] : 0;
        __syncthreads();
        s[t] += v;
        __syncthreads();
    }
    if (t < NB) bsum[t] = (t == 0) ? 0 : s[t - 1];
}

__global__ __launch_bounds__(256) void k_scanfin(const int* __restrict__ deg,
                                                 const int* __restrict__ bsum,
                                                 int* __restrict__ row_ptr,
                                                 int* __restrict__ fill)
{
    __shared__ int s[256];
    const int t = threadIdx.x;
    const int i = blockIdx.x * 256 + t;
    const int v = (i < NN) ? deg[i] : 0;
    s[t] = v;
    __syncthreads();
    for (int off = 1; off < 256; off <<= 1) {
        const int u = (t >= off) ? s[t - off] : 0;
        __syncthreads();
        s[t] += u;
        __syncthreads();
    }
    const int excl = s[t] - v + bsum[blockIdx.x];
    if (i < NN) { row_ptr[i] = excl; fill[i] = excl; }
    if (i == NN - 1) row_ptr[NN] = excl + v;
}

__global__ __launch_bounds__(256) void k_scatter(const int* __restrict__ ei,
                                                 int* __restrict__ fill,
                                                 int* __restrict__ ssrc)
{
    const int i = blockIdx.x * 256 + threadIdx.x;
    if (i >= NE) return;
    const int src = ei[i];
    const int dst = ei[NE + i];
    const int pos = atomicAdd(&fill[dst], 1);
    ssrc[pos] = src;
}

// ---------------------------------------------------------------------------
// k_agg: one wave per dst node; TWO edges per iteration (lane halves).
// Each half-wave owns one edge; lane u=lane&31 covers chans {2u,2u+1} via a
// packed uint read of ab. 4x unrolled -> 8 gathers in flight (2x the old MLP,
// half the serial chain). Softmax lane-parallel per 64-edge chunk (phase 1),
// per-edge q/src pulled via bpermute with per-half index. Cross-half z
// reduction via shfl_xor(32); zcat written as one uint4 per lane (half 0).
// ---------------------------------------------------------------------------
__global__ __launch_bounds__(256) void k_agg(
    const int* __restrict__ row_ptr, const int* __restrict__ ssrc,
    const float* __restrict__ t, const uint32* __restrict__ abu,
    const float* __restrict__ c, uint4* __restrict__ zcat4)
{
    const int lane = threadIdx.x & 63;
    const int node = (blockIdx.x * 256 + threadIdx.x) >> 6;
    if (node >= NN) return;

    const int half = lane >> 5;
    const int u = lane & 31;

    const int r0 = row_ptr[node];
    const int r1 = row_ptr[node + 1];
    const int deg = r1 - r0;
    const float invdeg = (deg > 0) ? 1.f / (float)deg : 0.f;

    const float4 tc = *(const float4*)c;
    const float4 td = ((const float4*)t)[node];

    // z[h][chan parity]: chans 2u (even) and 2u+1 (odd), heads 0..3
    float z00 = 0.f, z01 = 0.f, z10 = 0.f, z11 = 0.f;
    float z20 = 0.f, z21 = 0.f, z30 = 0.f, z31 = 0.f;

    for (int base = r0; base < r1; base += 64) {
        const int m = min(64, r1 - base);

        // phase 1: lane i computes softmax for edge base+i
        int src = 0;
        float q0 = 0.f, q1 = 0.f, q2 = 0.f, q3 = 0.f;
        if (lane < m) {
            src = ssrc[base + lane];
            const float4 ts = ((const float4*)t)[src];
            const float l0 = ts.x - td.x + tc.x;
            const float l1 = ts.y - td.y + tc.y;
            const float l2 = ts.z - td.z + tc.z;
            const float l3 = ts.w - td.w + tc.w;
            const float mx = fmaxf(fmaxf(l0, l1), fmaxf(l2, l3));
            const float e0 = __expf(l0 - mx);
            const float e1 = __expf(l1 - mx);
            const float e2 = __expf(l2 - mx);
            const float e3 = __expf(l3 - mx);
            const float s = invdeg / (e0 + e1 + e2 + e3);
            q0 = e0 * s; q1 = e1 * s; q2 = e2 * s; q3 = e3 * s;
        }

        // phase 2: 2 edges per step (one per half), 4 steps unrolled
        int e = 0;
        for (; e + 7 < m; e += 8) {
#pragma unroll
            for (int k = 0; k < 8; k += 2) {
                const int idx = e + k + half;
                const int se = __shfl(src, idx, 64);
                const float a0 = __shfl(q0, idx, 64);
                const float a1 = __shfl(q1, idx, 64);
                const float a2 = __shfl(q2, idx, 64);
                const float a3 = __shfl(q3, idx, 64);
                const uint32 av = abu[se * 32 + u];
                const float v0 = bf_lo(av), v1 = bf_hi(av);
                z00 += a0 * v0; z01 += a0 * v1;
                z10 += a1 * v0; z11 += a1 * v1;
                z20 += a2 * v0; z21 += a2 * v1;
                z30 += a3 * v0; z31 += a3 * v1;
            }
        }
        for (; e + 1 < m; e += 2) {
            const int idx = e + half;
            const int se = __shfl(src, idx, 64);
            const float a0 = __shfl(q0, idx, 64);
            const float a1 = __shfl(q1, idx, 64);
            const float a2 = __shfl(q2, idx, 64);
            const float a3 = __shfl(q3, idx, 64);
            const uint32 av = abu[se * 32 + u];
            const float v0 = bf_lo(av), v1 = bf_hi(av);
            z00 += a0 * v0; z01 += a0 * v1;
            z10 += a1 * v0; z11 += a1 * v1;
            z20 += a2 * v0; z21 += a2 * v1;
            z30 += a3 * v0; z31 += a3 * v1;
        }
        if (e < m) {   // final single edge: half 0 only
            const int se = __shfl(src, e, 64);
            const float a0 = __shfl(q0, e, 64);
            const float a1 = __shfl(q1, e, 64);
            const float a2 = __shfl(q2, e, 64);
            const float a3 = __shfl(q3, e, 64);
            if (half == 0) {
                const uint32 av = abu[se * 32 + u];
                const float v0 = bf_lo(av), v1 = bf_hi(av);
                z00 += a0 * v0; z01 += a0 * v1;
                z10 += a1 * v0; z11 += a1 * v1;
                z20 += a2 * v0; z21 += a2 * v1;
                z30 += a3 * v0; z31 += a3 * v1;
            }
        }
    }

    // cross-half reduction
    z00 += __shfl_xor(z00, 32, 64); z01 += __shfl_xor(z01, 32, 64);
    z10 += __shfl_xor(z10, 32, 64); z11 += __shfl_xor(z11, 32, 64);
    z20 += __shfl_xor(z20, 32, 64); z21 += __shfl_xor(z21, 32, 64);
    z30 += __shfl_xor(z30, 32, 64); z31 += __shfl_xor(z31, 32, 64);

    if (half == 0) {
        uint4 pk;
        pk.x = (uint32)f2bf(z00) | ((uint32)f2bf(z10) << 16);  // chan 2u, h0|h1
        pk.y = (uint32)f2bf(z20) | ((uint32)f2bf(z30) << 16);  // chan 2u, h2|h3
        pk.z = (uint32)f2bf(z01) | ((uint32)f2bf(z11) << 16);  // chan 2u+1
        pk.w = (uint32)f2bf(z21) | ((uint32)f2bf(z31) << 16);
        zcat4[node * 32 + u] = pk;   // 512B/wave contiguous
    }
}

// ---------------------------------------------------------------------------
// k_post (MFMA): out = relu(zcat @ Wp + bias + skip) + bf16 copy.
// B-frags from pre-packed global table (L2-hot) — no LDS, no repack.
// ---------------------------------------------------------------------------
__global__ __launch_bounds__(256) void k_post(
    const ushort16* __restrict__ zcat, const ushort16* __restrict__ pw,
    const float* __restrict__ bias, const float* __restrict__ skip,
    float* __restrict__ out, ushort16* __restrict__ outb)
{
    const int tid = threadIdx.x;
    const int lane = tid & 63;
    const int g = tid >> 6;
    const int m = lane & 15;
    const int quad = lane >> 4;
    const int rowBase = blockIdx.x * 64 + g * 16;

    const int arow = min(rowBase + m, NN - 1);
    const ushort16* zrow = zcat + (size_t)arow * 256 + quad * 8;

    f32x4 acc[4];
#pragma unroll
    for (int c = 0; c < 4; ++c)
#pragma unroll
        for (int r = 0; r < 4; ++r) acc[c][r] = 0.f;

#pragma unroll
    for (int s = 0; s < 8; ++s) {
        const bf16x8 af = *(const bf16x8*)(zrow + s * 32);
#pragma unroll
        for (int c = 0; c < 4; ++c) {
            const bf16x8 bf = *(const bf16x8*)&pw[((c * 8 + s) * 64 + lane) * 8];
            acc[c] = __builtin_amdgcn_mfma_f32_16x16x32_bf16(af, bf, acc[c], 0, 0, 0);
        }
    }

    // epilogue: row = quad*4+reg, col = c*16+m
#pragma unroll
    for (int c = 0; c < 4; ++c) {
        const int colg = c * 16 + m;
        const float bv = bias[colg];
#pragma unroll
        for (int reg = 0; reg < 4; ++reg) {
            const int gr = rowBase + quad * 4 + reg;
            if (gr < NN) {
                const float v = fmaxf(acc[c][reg] + bv + skip[gr * 64 + colg], 0.f);
                out[gr * 64 + colg]  = v;
                outb[gr * 64 + colg] = f2bf(v);
            }
        }
    }
}

extern "C" void kernel_launch(void* const* d_in, const int* in_sizes, int n_in,
                              void* d_out, int out_size, void* d_ws, size_t ws_size,
                              hipStream_t stream) {
    const float* x       = (const float*)d_in[0];
    const int*   ei      = (const int*)d_in[1];   // [2, NE] int32
    const float* lin1_w  = (const float*)d_in[2];
    const float* lin1_b  = (const float*)d_in[3];
    const float* lin2_w  = (const float*)d_in[4];
    const float* lin2_b  = (const float*)d_in[5];
    const float* lin3_w  = (const float*)d_in[6];
    const float* lin3_b  = (const float*)d_in[7];
    const float* conv1_w = (const float*)d_in[8];
    const float* conv1_u = (const float*)d_in[9];
    const float* conv1_c = (const float*)d_in[10];
    const float* conv1_bias = (const float*)d_in[11];
    const float* conv2_w = (const float*)d_in[12];
    const float* conv2_u = (const float*)d_in[13];
    const float* conv2_c = (const float*)d_in[14];
    const float* conv2_bias = (const float*)d_in[15];
    float* out = (float*)d_out;

    // workspace layout (~62 MB, 16B-aligned sections)
    char* p = (char*)d_ws;
    float* a      = (float*)p;           p += (size_t)NN * 64 * 4;   // fp32 a / h
    float* skip   = (float*)p;           p += (size_t)NN * 64 * 4;
    float* tt     = (float*)p;           p += (size_t)NN * 4 * 4;
    ushort16* ab  = (ushort16*)p;        p += (size_t)NN * 64 * 2;   // bf16 a / h
    ushort16* zc  = (ushort16*)p;        p += (size_t)NN * 256 * 2;  // bf16 z
    ushort16* pw12 = (ushort16*)p;       p += 16384 * 2;             // packed [W1|W2]
    ushort16* pwc1 = (ushort16*)p;       p += 16384 * 2;             // packed conv1_w
    ushort16* pwc2 = (ushort16*)p;       p += 16384 * 2;             // packed conv2_w
    int* ssrc     = (int*)p;             p += (size_t)NE * 4;
    int* deg      = (int*)p;             p += (size_t)NN * 4;
    int* row_ptr  = (int*)p;             p += (size_t)(NN + 1) * 4;
    int* fill     = (int*)p;             p += (size_t)NN * 4;
    int* bsum     = (int*)p;

    // ---- weight pre-pack (tiny) + CSR build ----
    k_pack12<<<64, 256, 0, stream>>>(lin1_w, lin2_w, pw12);
    k_packp<<<64, 256, 0, stream>>>(conv1_w, pwc1);
    k_packp<<<64, 256, 0, stream>>>(conv2_w, pwc2);
    hipMemsetAsync(deg, 0, (size_t)NN * sizeof(int), stream);
    k_hist<<<(NE + 255) / 256, 256, 0, stream>>>(ei, deg);
    k_blocksum<<<NB, 256, 0, stream>>>(deg, bsum);
    k_scanb<<<1, 256, 0, stream>>>(bsum);
    k_scanfin<<<NB, 256, 0, stream>>>(deg, bsum, row_ptr, fill);
    k_scatter<<<(NE + 255) / 256, 256, 0, stream>>>(ei, fill, ssrc);

    // ---- layer 1 ----
    k_lin12<<<(NN + 63) / 64, 256, 0, stream>>>(x, pw12, lin1_b, lin2_b, a, ab, skip);
    k_t<<<(NN * 4 + 255) / 256, 256, 0, stream>>>(a, conv1_u, tt);
    k_agg<<<(NN + 3) / 4, 256, 0, stream>>>(row_ptr, ssrc, tt, (const uint32*)ab,
                                            conv1_c, (uint4*)zc);
    k_post<<<(NN + 63) / 64, 256, 0, stream>>>(zc, pwc1, conv1_bias, skip, a, ab);

    // ---- layer 2 ---- (h fp32 in a, bf16 in ab)
    k_t<<<(NN * 4 + 255) / 256, 256, 0, stream>>>(a, conv2_u, tt);
    k_lin3<<<(NN + 31) / 32, 256, 0, stream>>>(a, lin3_w, lin3_b, skip);
    k_agg<<<(NN + 3) / 4, 256, 0, stream>>>(row_ptr, ssrc, tt, (const uint32*)ab,
                                            conv2_c, (uint4*)zc);
    k_post<<<(NN + 63) / 64, 256, 0, stream>>>(zc, pwc2, conv2_bias, skip, out, ab);
}

// Round 14
// 335.230 us; speedup vs baseline: 1.5890x; 1.0572x over previous
//
#include <hip/hip_runtime.h>

#define NN 50000
#define NE 800000
#define NB ((NN + 255) / 256)   // 196 scan blocks

typedef unsigned int uint32;
typedef unsigned short ushort16;
typedef __attribute__((ext_vector_type(8))) short bf16x8;
typedef __attribute__((ext_vector_type(4))) float f32x4;

__device__ __forceinline__ ushort16 f2bf(float f) {
    uint32 u = __float_as_uint(f);
    u += 0x7fff + ((u >> 16) & 1);      // round-to-nearest-even
    return (ushort16)(u >> 16);
}
__device__ __forceinline__ float bf2f(ushort16 h) {
    return __uint_as_float(((uint32)h) << 16);
}
__device__ __forceinline__ float bf_lo(uint32 u) {
    return __uint_as_float(u << 16);
}
__device__ __forceinline__ float bf_hi(uint32 u) {
    return __uint_as_float(u & 0xffff0000u);
}
__device__ __forceinline__ bf16x8 pack8(const float4 a, const float4 b) {
    union { bf16x8 v; ushort16 u[8]; } r;
    r.u[0] = f2bf(a.x); r.u[1] = f2bf(a.y); r.u[2] = f2bf(a.z); r.u[3] = f2bf(a.w);
    r.u[4] = f2bf(b.x); r.u[5] = f2bf(b.y); r.u[6] = f2bf(b.z); r.u[7] = f2bf(b.w);
    return r.v;
}

// ---------------------------------------------------------------------------
// Weight pre-pack (once per launch): fp32 -> bf16 B-fragment order tables.
// ---------------------------------------------------------------------------
__global__ __launch_bounds__(256) void k_pack12(
    const float* __restrict__ w1, const float* __restrict__ w2,
    ushort16* __restrict__ pw)
{
    const int i = blockIdx.x * 256 + threadIdx.x;   // 0..16383
    const int j  = i & 7;
    const int ln = (i >> 3) & 63;
    const int s  = (i >> 9) & 3;
    const int cc = i >> 11;
    const int k  = s * 32 + ((ln >> 4) * 8) + j;    // 0..127
    const int n  = cc * 16 + (ln & 15);             // 0..127
    pw[i] = f2bf((n < 64) ? w1[k * 64 + n] : w2[k * 64 + (n - 64)]);
}

__global__ __launch_bounds__(256) void k_packp(
    const float* __restrict__ w, ushort16* __restrict__ pw)
{
    const int i = blockIdx.x * 256 + threadIdx.x;   // 0..16383
    const int j  = i & 7;
    const int ln = (i >> 3) & 63;
    const int s  = (i >> 9) & 7;
    const int cc = i >> 12;
    const int k  = s * 32 + ((ln >> 4) * 8) + j;    // zcat idx (k-dim)
    const int n  = cc * 16 + (ln & 15);             // output col
    pw[i] = f2bf(w[(k >> 2) * 256 + (k & 3) * 64 + n]);
}

__global__ __launch_bounds__(256) void k_packl3(
    const float* __restrict__ w, ushort16* __restrict__ pw)
{
    const int i = blockIdx.x * 256 + threadIdx.x;   // 0..4095
    const int j  = i & 7;
    const int ln = (i >> 3) & 63;
    const int s  = (i >> 9) & 1;
    const int cc = i >> 10;                         // 0..3
    const int k  = s * 32 + ((ln >> 4) * 8) + j;    // 0..63
    const int n  = cc * 16 + (ln & 15);             // 0..63
    pw[i] = f2bf(w[k * 64 + n]);
}

// ---------------------------------------------------------------------------
// k_lin12 (MFMA): [a | skip] = x @ [W1 | W2] + [b1 | b2]; a also emitted bf16.
// B-frags from pre-packed global table (L2-hot). 64 rows/block; 32 MFMA/wave.
// C/D: col=lane&15 (+16*c), row=quad*4+reg (verified mapping).
// ---------------------------------------------------------------------------
__global__ __launch_bounds__(256) void k_lin12(
    const float* __restrict__ x, const ushort16* __restrict__ pw,
    const float* __restrict__ b1, const float* __restrict__ b2,
    float* __restrict__ a, ushort16* __restrict__ ab, float* __restrict__ skip)
{
    const int tid = threadIdx.x;
    const int lane = tid & 63;
    const int g = tid >> 6;
    const int m = lane & 15;
    const int quad = lane >> 4;
    const int rowBase = blockIdx.x * 64 + g * 16;

    const int arow = min(rowBase + m, NN - 1);
    const float* xr = x + (size_t)arow * 128 + quad * 8;

    f32x4 acc[8];
#pragma unroll
    for (int c = 0; c < 8; ++c)
#pragma unroll
        for (int r = 0; r < 4; ++r) acc[c][r] = 0.f;

#pragma unroll
    for (int s = 0; s < 4; ++s) {
        const float4 xa = *(const float4*)(xr + s * 32);
        const float4 xb = *(const float4*)(xr + s * 32 + 4);
        const bf16x8 af = pack8(xa, xb);
#pragma unroll
        for (int c = 0; c < 8; ++c) {
            const bf16x8 bf = *(const bf16x8*)&pw[((c * 4 + s) * 64 + lane) * 8];
            acc[c] = __builtin_amdgcn_mfma_f32_16x16x32_bf16(af, bf, acc[c], 0, 0, 0);
        }
    }

#pragma unroll
    for (int c = 0; c < 8; ++c) {
        const int colg = c * 16 + m;
        const float bv = (colg < 64) ? b1[colg] : b2[colg - 64];
#pragma unroll
        for (int reg = 0; reg < 4; ++reg) {
            const int gr = rowBase + quad * 4 + reg;
            if (gr < NN) {
                const float v = acc[c][reg] + bv;
                if (colg < 64) {
                    a[gr * 64 + colg]  = v;
                    ab[gr * 64 + colg] = f2bf(v);
                } else {
                    skip[gr * 64 + (colg - 64)] = v;
                }
            }
        }
    }
}

// ---------------------------------------------------------------------------
// k_t: t[n,h] = a[n,:] @ u[:,h]   ([NN,64]@[64,4]) — one thread per (n,h)
// ---------------------------------------------------------------------------
__global__ __launch_bounds__(256) void k_t(
    const float* __restrict__ a, const float* __restrict__ u,
    float* __restrict__ t)
{
    const int gid = blockIdx.x * 256 + threadIdx.x;
    if (gid >= NN * 4) return;
    const int n = gid >> 2, h = gid & 3;
    const float* ar = a + n * 64;
    float s = 0.f;
#pragma unroll 4
    for (int k = 0; k < 64; ++k) s += ar[k] * u[k * 4 + h];
    t[gid] = s;
}

// ---------------------------------------------------------------------------
// k_lin3m (MFMA): skip = h_bf16 @ W3 + b3  ([NN,64]@[64,64], K=64).
// A-frags straight from ab rows (16B loads); B-frags pre-packed. 8 MFMA/wave.
// ---------------------------------------------------------------------------
__global__ __launch_bounds__(256) void k_lin3m(
    const ushort16* __restrict__ hb, const ushort16* __restrict__ pw,
    const float* __restrict__ b, float* __restrict__ outp)
{
    const int tid = threadIdx.x;
    const int lane = tid & 63;
    const int g = tid >> 6;
    const int m = lane & 15;
    const int quad = lane >> 4;
    const int rowBase = blockIdx.x * 64 + g * 16;

    const int arow = min(rowBase + m, NN - 1);
    const ushort16* zrow = hb + (size_t)arow * 64 + quad * 8;

    f32x4 acc[4];
#pragma unroll
    for (int c = 0; c < 4; ++c)
#pragma unroll
        for (int r = 0; r < 4; ++r) acc[c][r] = 0.f;

#pragma unroll
    for (int s = 0; s < 2; ++s) {
        const bf16x8 af = *(const bf16x8*)(zrow + s * 32);
#pragma unroll
        for (int c = 0; c < 4; ++c) {
            const bf16x8 bf = *(const bf16x8*)&pw[((c * 2 + s) * 64 + lane) * 8];
            acc[c] = __builtin_amdgcn_mfma_f32_16x16x32_bf16(af, bf, acc[c], 0, 0, 0);
        }
    }

#pragma unroll
    for (int c = 0; c < 4; ++c) {
        const int colg = c * 16 + m;
        const float bv = b[colg];
#pragma unroll
        for (int reg = 0; reg < 4; ++reg) {
            const int gr = rowBase + quad * 4 + reg;
            if (gr < NN) outp[gr * 64 + colg] = acc[c][reg] + bv;
        }
    }
}

// ---------------------------------------------------------------------------
// CSR build: histogram -> hierarchical scan -> scatter (src only, 4B)
// hist & scatter batched x4: 4 independent atomic chains in flight/thread.
// ---------------------------------------------------------------------------
__global__ __launch_bounds__(256) void k_hist(const int* __restrict__ ei,
                                              int* __restrict__ deg)
{
    const int i0 = (blockIdx.x * 256 + threadIdx.x) * 4;
    if (i0 + 3 < NE) {
        const int4 d4 = *(const int4*)&ei[NE + i0];
        atomicAdd(&deg[d4.x], 1);
        atomicAdd(&deg[d4.y], 1);
        atomicAdd(&deg[d4.z], 1);
        atomicAdd(&deg[d4.w], 1);
    } else {
        for (int i = i0; i < NE; ++i) atomicAdd(&deg[ei[NE + i]], 1);
    }
}

__global__ __launch_bounds__(256) void k_blocksum(const int* __restrict__ deg,
                                                  int* __restrict__ bsum)
{
    __shared__ int red[256];
    const int t = threadIdx.x;
    const int i = blockIdx.x * 256 + t;
    red[t] = (i < NN) ? deg[i] : 0;
    __syncthreads();
    for (int off = 128; off > 0; off >>= 1) {
        if (t < off) red[t] += red[t + off];
        __syncthreads();
    }
    if (t == 0) bsum[blockIdx.x] = red[0];
}

__global__ __launch_bounds__(256) void k_scanb(int* __restrict__ bsum)
{
    __shared__ int s[256];
    const int t = threadIdx.x;
    s[t] = (t < NB) ? bsum[t] : 0;
    __syncthreads();
    for (int off = 1; off < 256; off <<= 1) {
        const int v = (t >= off) ? s[t - off] : 0;
        __syncthreads();
        s[t] += v;
        __syncthreads();
    }
    if (t < NB) bsum[t] = (t == 0) ? 0 : s[t - 1];
}

__global__ __launch_bounds__(256) void k_scanfin(const int* __restrict__ deg,
                                                 const int* __restrict__ bsum,
                                                 int* __restrict__ row_ptr,
                                                 int* __restrict__ fill)
{
    __shared__ int s[256];
    const int t = threadIdx.x;
    const int i = blockIdx.x * 256 + t;
    const int v = (i < NN) ? deg[i] : 0;
    s[t] = v;
    __syncthreads();
    for (int off = 1; off < 256; off <<= 1) {
        const int u = (t >= off) ? s[t - off] : 0;
        __syncthreads();
        s[t] += u;
        __syncthreads();
    }
    const int excl = s[t] - v + bsum[blockIdx.x];
    if (i < NN) { row_ptr[i] = excl; fill[i] = excl; }
    if (i == NN - 1) row_ptr[NN] = excl + v;
}

__global__ __launch_bounds__(256) void k_scatter(const int* __restrict__ ei,
                                                 int* __restrict__ fill,
                                                 int* __restrict__ ssrc)
{
    const int i0 = (blockIdx.x * 256 + threadIdx.x) * 4;
    if (i0 + 3 < NE) {
        const int4 s4 = *(const int4*)&ei[i0];
        const int4 d4 = *(const int4*)&ei[NE + i0];
        const int p0 = atomicAdd(&fill[d4.x], 1);
        const int p1 = atomicAdd(&fill[d4.y], 1);
        const int p2 = atomicAdd(&fill[d4.z], 1);
        const int p3 = atomicAdd(&fill[d4.w], 1);
        ssrc[p0] = s4.x;
        ssrc[p1] = s4.y;
        ssrc[p2] = s4.z;
        ssrc[p3] = s4.w;
    } else {
        for (int i = i0; i < NE; ++i) {
            const int pos = atomicAdd(&fill[ei[NE + i]], 1);
            ssrc[pos] = ei[i];
        }
    }
}

// ---------------------------------------------------------------------------
// k_agg: one wave per dst node; TWO edges per iteration (lane halves), each
// half-lane covers chans {2u,2u+1} via packed uint reads of ab. Softmax
// lane-parallel per 64-edge chunk; q/src broadcast via shfl. Cross-half z
// reduction via shfl_xor(32); zcat written as one uint4 per lane (half 0).
// ---------------------------------------------------------------------------
__global__ __launch_bounds__(256) void k_agg(
    const int* __restrict__ row_ptr, const int* __restrict__ ssrc,
    const float* __restrict__ t, const uint32* __restrict__ abu,
    const float* __restrict__ c, uint4* __restrict__ zcat4)
{
    const int lane = threadIdx.x & 63;
    const int node = (blockIdx.x * 256 + threadIdx.x) >> 6;
    if (node >= NN) return;

    const int half = lane >> 5;
    const int u = lane & 31;

    const int r0 = row_ptr[node];
    const int r1 = row_ptr[node + 1];
    const int deg = r1 - r0;
    const float invdeg = (deg > 0) ? 1.f / (float)deg : 0.f;

    const float4 tc = *(const float4*)c;
    const float4 td = ((const float4*)t)[node];

    float z00 = 0.f, z01 = 0.f, z10 = 0.f, z11 = 0.f;
    float z20 = 0.f, z21 = 0.f, z30 = 0.f, z31 = 0.f;

    for (int base = r0; base < r1; base += 64) {
        const int m = min(64, r1 - base);

        int src = 0;
        float q0 = 0.f, q1 = 0.f, q2 = 0.f, q3 = 0.f;
        if (lane < m) {
            src = ssrc[base + lane];
            const float4 ts = ((const float4*)t)[src];
            const float l0 = ts.x - td.x + tc.x;
            const float l1 = ts.y - td.y + tc.y;
            const float l2 = ts.z - td.z + tc.z;
            const float l3 = ts.w - td.w + tc.w;
            const float mx = fmaxf(fmaxf(l0, l1), fmaxf(l2, l3));
            const float e0 = __expf(l0 - mx);
            const float e1 = __expf(l1 - mx);
            const float e2 = __expf(l2 - mx);
            const float e3 = __expf(l3 - mx);
            const float s = invdeg / (e0 + e1 + e2 + e3);
            q0 = e0 * s; q1 = e1 * s; q2 = e2 * s; q3 = e3 * s;
        }

        int e = 0;
        for (; e + 7 < m; e += 8) {
#pragma unroll
            for (int k = 0; k < 8; k += 2) {
                const int idx = e + k + half;
                const int se = __shfl(src, idx, 64);
                const float a0 = __shfl(q0, idx, 64);
                const float a1 = __shfl(q1, idx, 64);
                const float a2 = __shfl(q2, idx, 64);
                const float a3 = __shfl(q3, idx, 64);
                const uint32 av = abu[se * 32 + u];
                const float v0 = bf_lo(av), v1 = bf_hi(av);
                z00 += a0 * v0; z01 += a0 * v1;
                z10 += a1 * v0; z11 += a1 * v1;
                z20 += a2 * v0; z21 += a2 * v1;
                z30 += a3 * v0; z31 += a3 * v1;
            }
        }
        for (; e + 1 < m; e += 2) {
            const int idx = e + half;
            const int se = __shfl(src, idx, 64);
            const float a0 = __shfl(q0, idx, 64);
            const float a1 = __shfl(q1, idx, 64);
            const float a2 = __shfl(q2, idx, 64);
            const float a3 = __shfl(q3, idx, 64);
            const uint32 av = abu[se * 32 + u];
            const float v0 = bf_lo(av), v1 = bf_hi(av);
            z00 += a0 * v0; z01 += a0 * v1;
            z10 += a1 * v0; z11 += a1 * v1;
            z20 += a2 * v0; z21 += a2 * v1;
            z30 += a3 * v0; z31 += a3 * v1;
        }
        if (e < m) {
            const int se = __shfl(src, e, 64);
            const float a0 = __shfl(q0, e, 64);
            const float a1 = __shfl(q1, e, 64);
            const float a2 = __shfl(q2, e, 64);
            const float a3 = __shfl(q3, e, 64);
            if (half == 0) {
                const uint32 av = abu[se * 32 + u];
                const float v0 = bf_lo(av), v1 = bf_hi(av);
                z00 += a0 * v0; z01 += a0 * v1;
                z10 += a1 * v0; z11 += a1 * v1;
                z20 += a2 * v0; z21 += a2 * v1;
                z30 += a3 * v0; z31 += a3 * v1;
            }
        }
    }

    z00 += __shfl_xor(z00, 32, 64); z01 += __shfl_xor(z01, 32, 64);
    z10 += __shfl_xor(z10, 32, 64); z11 += __shfl_xor(z11, 32, 64);
    z20 += __shfl_xor(z20, 32, 64); z21 += __shfl_xor(z21, 32, 64);
    z30 += __shfl_xor(z30, 32, 64); z31 += __shfl_xor(z31, 32, 64);

    if (half == 0) {
        uint4 pk;
        pk.x = (uint32)f2bf(z00) | ((uint32)f2bf(z10) << 16);
        pk.y = (uint32)f2bf(z20) | ((uint32)f2bf(z30) << 16);
        pk.z = (uint32)f2bf(z01) | ((uint32)f2bf(z11) << 16);
        pk.w = (uint32)f2bf(z21) | ((uint32)f2bf(z31) << 16);
        zcat4[node * 32 + u] = pk;
    }
}

// ---------------------------------------------------------------------------
// k_post (MFMA): out = relu(zcat @ Wp + bias + skip) + bf16 copy.
// ---------------------------------------------------------------------------
__global__ __launch_bounds__(256) void k_post(
    const ushort16* __restrict__ zcat, const ushort16* __restrict__ pw,
    const float* __restrict__ bias, const float* __restrict__ skip,
    float* __restrict__ out, ushort16* __restrict__ outb)
{
    const int tid = threadIdx.x;
    const int lane = tid & 63;
    const int g = tid >> 6;
    const int m = lane & 15;
    const int quad = lane >> 4;
    const int rowBase = blockIdx.x * 64 + g * 16;

    const int arow = min(rowBase + m, NN - 1);
    const ushort16* zrow = zcat + (size_t)arow * 256 + quad * 8;

    f32x4 acc[4];
#pragma unroll
    for (int c = 0; c < 4; ++c)
#pragma unroll
        for (int r = 0; r < 4; ++r) acc[c][r] = 0.f;

#pragma unroll
    for (int s = 0; s < 8; ++s) {
        const bf16x8 af = *(const bf16x8*)(zrow + s * 32);
#pragma unroll
        for (int c = 0; c < 4; ++c) {
            const bf16x8 bf = *(const bf16x8*)&pw[((c * 8 + s) * 64 + lane) * 8];
            acc[c] = __builtin_amdgcn_mfma_f32_16x16x32_bf16(af, bf, acc[c], 0, 0, 0);
        }
    }

#pragma unroll
    for (int c = 0; c < 4; ++c) {
        const int colg = c * 16 + m;
        const float bv = bias[colg];
#pragma unroll
        for (int reg = 0; reg < 4; ++reg) {
            const int gr = rowBase + quad * 4 + reg;
            if (gr < NN) {
                const float v = fmaxf(acc[c][reg] + bv + skip[gr * 64 + colg], 0.f);
                out[gr * 64 + colg]  = v;
                outb[gr * 64 + colg] = f2bf(v);
            }
        }
    }
}

extern "C" void kernel_launch(void* const* d_in, const int* in_sizes, int n_in,
                              void* d_out, int out_size, void* d_ws, size_t ws_size,
                              hipStream_t stream) {
    const float* x       = (const float*)d_in[0];
    const int*   ei      = (const int*)d_in[1];   // [2, NE] int32
    const float* lin1_w  = (const float*)d_in[2];
    const float* lin1_b  = (const float*)d_in[3];
    const float* lin2_w  = (const float*)d_in[4];
    const float* lin2_b  = (const float*)d_in[5];
    const float* lin3_w  = (const float*)d_in[6];
    const float* lin3_b  = (const float*)d_in[7];
    const float* conv1_w = (const float*)d_in[8];
    const float* conv1_u = (const float*)d_in[9];
    const float* conv1_c = (const float*)d_in[10];
    const float* conv1_bias = (const float*)d_in[11];
    const float* conv2_w = (const float*)d_in[12];
    const float* conv2_u = (const float*)d_in[13];
    const float* conv2_c = (const float*)d_in[14];
    const float* conv2_bias = (const float*)d_in[15];
    float* out = (float*)d_out;

    // workspace layout (~62 MB, 16B-aligned sections)
    char* p = (char*)d_ws;
    float* a      = (float*)p;           p += (size_t)NN * 64 * 4;   // fp32 a / h
    float* skip   = (float*)p;           p += (size_t)NN * 64 * 4;
    float* tt     = (float*)p;           p += (size_t)NN * 4 * 4;
    ushort16* ab  = (ushort16*)p;        p += (size_t)NN * 64 * 2;   // bf16 a / h
    ushort16* zc  = (ushort16*)p;        p += (size_t)NN * 256 * 2;  // bf16 z
    ushort16* pw12 = (ushort16*)p;       p += 16384 * 2;             // packed [W1|W2]
    ushort16* pwc1 = (ushort16*)p;       p += 16384 * 2;             // packed conv1_w
    ushort16* pwc2 = (ushort16*)p;       p += 16384 * 2;             // packed conv2_w
    ushort16* pwl3 = (ushort16*)p;       p += 4096 * 2;              // packed lin3_w
    int* ssrc     = (int*)p;             p += (size_t)NE * 4;
    int* deg      = (int*)p;             p += (size_t)NN * 4;
    int* row_ptr  = (int*)p;             p += (size_t)(NN + 1) * 4;
    int* fill     = (int*)p;             p += (size_t)NN * 4;
    int* bsum     = (int*)p;

    // ---- weight pre-pack (tiny) + CSR build ----
    k_pack12<<<64, 256, 0, stream>>>(lin1_w, lin2_w, pw12);
    k_packp<<<64, 256, 0, stream>>>(conv1_w, pwc1);
    k_packp<<<64, 256, 0, stream>>>(conv2_w, pwc2);
    k_packl3<<<16, 256, 0, stream>>>(lin3_w, pwl3);
    hipMemsetAsync(deg, 0, (size_t)NN * sizeof(int), stream);
    k_hist<<<(NE / 4 + 255) / 256, 256, 0, stream>>>(ei, deg);
    k_blocksum<<<NB, 256, 0, stream>>>(deg, bsum);
    k_scanb<<<1, 256, 0, stream>>>(bsum);
    k_scanfin<<<NB, 256, 0, stream>>>(deg, bsum, row_ptr, fill);
    k_scatter<<<(NE / 4 + 255) / 256, 256, 0, stream>>>(ei, fill, ssrc);

    // ---- layer 1 ----
    k_lin12<<<(NN + 63) / 64, 256, 0, stream>>>(x, pw12, lin1_b, lin2_b, a, ab, skip);
    k_t<<<(NN * 4 + 255) / 256, 256, 0, stream>>>(a, conv1_u, tt);
    k_agg<<<(NN + 3) / 4, 256, 0, stream>>>(row_ptr, ssrc, tt, (const uint32*)ab,
                                            conv1_c, (uint4*)zc);
    k_post<<<(NN + 63) / 64, 256, 0, stream>>>(zc, pwc1, conv1_bias, skip, a, ab);

    // ---- layer 2 ---- (h fp32 in a, bf16 in ab)
    k_t<<<(NN * 4 + 255) / 256, 256, 0, stream>>>(a, conv2_u, tt);
    k_lin3m<<<(NN + 63) / 64, 256, 0, stream>>>(ab, pwl3, lin3_b, skip);
    k_agg<<<(NN + 3) / 4, 256, 0, stream>>>(row_ptr, ssrc, tt, (const uint32*)ab,
                                            conv2_c, (uint4*)zc);
    k_post<<<(NN + 63) / 64, 256, 0, stream>>>(zc, pwc2, conv2_bias, skip, out, ab);
}